// Round 7
// baseline (464.105 us; speedup 1.0000x reference)
//
#include <hip/hip_runtime.h>

#define NN 50000
#define NE 800000
#define DD 96
#define NEG 0.01f
#define FN 64       // nodes per fuse4 block
#define XST 104     // LDS row stride (bf16 units): 208 B, 16B-aligned
#define CAP 44      // staged edges per row (P(deg>44) ~ 1e-10; overflow path below)

typedef __attribute__((ext_vector_type(8))) short short8v;
typedef __attribute__((ext_vector_type(4))) short short4v;
typedef __attribute__((ext_vector_type(4))) float f32x4;

static __device__ __forceinline__ float lrelu(float x) {
  return (x >= 0.f) ? x : NEG * x;
}
static __device__ __forceinline__ void fma4(float4& a, float v, const float4& x) {
  a.x += v * x.x; a.y += v * x.y; a.z += v * x.z; a.w += v * x.w;
}
static __device__ __forceinline__ unsigned short f2bf(float x) {
  unsigned u = __float_as_uint(x);
  u += 0x7fffu + ((u >> 16) & 1u);   // RNE
  return (unsigned short)(u >> 16);
}
static __device__ __forceinline__ float bf2f(unsigned short h) {
  return __uint_as_float(((unsigned)h) << 16);
}

// ================= fallback (round-1) path =================
__global__ __launch_bounds__(256) void scatter_kernel(
    const float* __restrict__ ego, const float* __restrict__ avals,
    const int* __restrict__ arows, const int* __restrict__ acols,
    float* __restrict__ side)
{
  int t = blockIdx.x * 256 + threadIdx.x;
  int e = t >> 5;
  int lane = t & 31;
  if (e >= NE) return;
  int row = arows[e];
  int col = acols[e];
  float v = avals[e];
  if (lane < 24) {
    const float4* src = (const float4*)(ego + (size_t)col * DD);
    float4 x = src[lane];
    float* dst = side + (size_t)row * DD + lane * 4;
    unsafeAtomicAdd(dst + 0, v * x.x);
    unsafeAtomicAdd(dst + 1, v * x.y);
    unsafeAtomicAdd(dst + 2, v * x.z);
    unsafeAtomicAdd(dst + 3, v * x.w);
  }
}

__global__ __launch_bounds__(192) void fuse_fb_kernel(
    const float* __restrict__ ego, const float* __restrict__ side,
    const float* __restrict__ W1, const float* __restrict__ b1,
    const float* __restrict__ W2, const float* __restrict__ b2,
    float* __restrict__ out)
{
  __shared__ float W1t[DD * DD];
  __shared__ float W2t[DD * DD];
  __shared__ float b1s[DD], b2s[DD];
  __shared__ float xs[192], ys[192];
  int tid = threadIdx.x;
  for (int i = tid; i < DD * DD; i += 192) {
    int j = i / DD, k = i - j * DD;
    W1t[k * DD + j] = W1[i];
    W2t[k * DD + j] = W2[i];
  }
  if (tid < DD) { b1s[tid] = b1[tid]; b2s[tid] = b2[tid]; }
  __syncthreads();
  int nl = tid / DD, j = tid - nl * DD;
  for (int p = blockIdx.x; p < NN / 2; p += gridDim.x) {
    int base = p * 192;
    float e = ego[base + tid], s = side[base + tid];
    xs[tid] = e + s; ys[tid] = e * s;
    __syncthreads();
    float a1 = b1s[j], a2 = b2s[j];
    const float* xr = xs + nl * DD;
    const float* yr = ys + nl * DD;
#pragma unroll 16
    for (int k = 0; k < DD; ++k) {
      a1 += xr[k] * W1t[k * DD + j];
      a2 += yr[k] * W2t[k * DD + j];
    }
    float r = lrelu(a1) + lrelu(a2);
    __syncthreads();
    out[base + tid] = r;
  }
}

// ========== prep: per-row linked list + W->bf16 + ego->bf16 ==========
// next[e] written COALESCED at index e (no scattered 8B stores -> no
// partial-line write-back amplification). head is 200 KB, L2-resident.
#define NB_CNT (NE / 256)          // 3125
#define NB_W   ((DD * DD) / 256)   // 36
#define NE4    (NN * DD / 4)       // 1200000 float4 units
#define NB_E   ((NE4 + 255) / 256) // 4688
__global__ __launch_bounds__(256) void prep_kernel(
    const int* __restrict__ rows, int* __restrict__ head, int* __restrict__ nxt,
    const float* __restrict__ W1, const float* __restrict__ W2,
    unsigned short* __restrict__ Wb1, unsigned short* __restrict__ Wb2,
    const float* __restrict__ ego, unsigned short* __restrict__ egob)
{
  int b = blockIdx.x;
  if (b < NB_CNT) {
    int e = b * 256 + threadIdx.x;
    int r = rows[e];
    nxt[e] = atomicExch(&head[r], e);   // lock-free prepend
  } else if (b < NB_CNT + NB_W) {
    int i = (b - NB_CNT) * 256 + threadIdx.x;  // [0, 9216)
    Wb1[i] = f2bf(W1[i]);
    Wb2[i] = f2bf(W2[i]);
  } else {
    int i = (b - NB_CNT - NB_W) * 256 + threadIdx.x;
    if (i < NE4) {
      float4 v = ((const float4*)ego)[i];
      short4v o;
      o.x = (short)f2bf(v.x); o.y = (short)f2bf(v.y);
      o.z = (short)f2bf(v.z); o.w = (short)f2bf(v.w);
      ((short4v*)egob)[i] = o;
    }
  }
}

// ====== agg5: parallel chain walk (64 chains/wave) + gather/FMA ======
// 128 thr = 2 waves; each wave owns 64 rows. Phase 1: lane r walks row r's
// chain (independent chains -> full MLP), staging edge ids in LDS.
// Phase 2: per row, half-split 4-deep gather+fma (same pattern as R5 agg).
__global__ __launch_bounds__(128) void agg5_kernel(
    const unsigned short* __restrict__ egob,
    const int* __restrict__ head, const int* __restrict__ nxt,
    const int* __restrict__ acols, const float* __restrict__ avals,
    float* __restrict__ side)
{
  __shared__ int eids[2][64][CAP];
  __shared__ int lens[2][64];
  __shared__ int ovh[2][64];

  int tid = threadIdx.x;
  int w = tid >> 6, lane = tid & 63;
  int rowbase = blockIdx.x * 128 + w * 64;
  int row = rowbase + lane;

  int cnt = 0, ov = -1;
  if (row < NN) {
    int e = head[row];
    while (e >= 0 && cnt < CAP) {
      eids[w][lane][cnt++] = e;
      e = nxt[e];
    }
    ov = e;  // -1 unless degree > CAP (essentially never)
  }
  lens[w][lane] = cnt;
  ovh[w][lane] = ov;
  __syncthreads();

  int half = lane >> 5, hl = lane & 31;

  for (int rr = 0; rr < 64; ++rr) {
    int r2 = rowbase + rr;
    if (r2 >= NN) break;
    int L = lens[w][rr];

    float4 a[4];
#pragma unroll
    for (int d = 0; d < 4; ++d) a[d] = make_float4(0.f, 0.f, 0.f, 0.f);

    // 8 edges in flight: half h takes slots i + 2d + h, d-depth 4
    for (int i = 0; i < L; i += 8) {
#pragma unroll
      for (int d = 0; d < 4; ++d) {
        int slot = i + 2 * d + half;
        int c = 0; float v = 0.f;
        if (slot < L) {
          int e = eids[w][rr][slot];
          c = acols[e];
          v = avals[e];
        }
        if (hl < 24) {
          short4v x = ((const short4v*)(egob + (size_t)c * DD))[hl];
          float4 xf = make_float4(bf2f((unsigned short)x.x),
                                  bf2f((unsigned short)x.y),
                                  bf2f((unsigned short)x.z),
                                  bf2f((unsigned short)x.w));
          fma4(a[d], v, xf);
        }
      }
    }

    // overflow remainder (uniform loop, ~never taken)
    int ove = ovh[w][rr];
    while (ove >= 0) {
      int c = acols[ove];
      float v = avals[ove];
      if (half == 0 && hl < 24) {
        short4v x = ((const short4v*)(egob + (size_t)c * DD))[hl];
        float4 xf = make_float4(bf2f((unsigned short)x.x),
                                bf2f((unsigned short)x.y),
                                bf2f((unsigned short)x.z),
                                bf2f((unsigned short)x.w));
        fma4(a[0], v, xf);
      }
      ove = nxt[ove];
    }

    float4 acc;
    acc.x = (a[0].x + a[1].x) + (a[2].x + a[3].x);
    acc.y = (a[0].y + a[1].y) + (a[2].y + a[3].y);
    acc.z = (a[0].z + a[1].z) + (a[2].z + a[3].z);
    acc.w = (a[0].w + a[1].w) + (a[2].w + a[3].w);
    acc.x += __shfl(acc.x, lane ^ 32, 64);
    acc.y += __shfl(acc.y, lane ^ 32, 64);
    acc.z += __shfl(acc.z, lane ^ 32, 64);
    acc.w += __shfl(acc.w, lane ^ 32, 64);
    if (half == 0 && hl < 24)
      *((float4*)(side + (size_t)r2 * DD) + hl) = acc;
  }
}

// ========== fused bi-interaction via bf16 MFMA (unchanged, verified) ==========
__global__ __launch_bounds__(256) void fuse4_kernel(
    const float* __restrict__ ego, const float* __restrict__ side,
    const unsigned short* __restrict__ Wb1, const unsigned short* __restrict__ Wb2,
    const float* __restrict__ b1, const float* __restrict__ b2,
    float* __restrict__ out)
{
  __shared__ unsigned short xs[FN * XST];
  __shared__ unsigned short ys[FN * XST];
  int tid = threadIdx.x;
  int nbase = blockIdx.x * FN;

  for (int i = tid; i < FN * 24; i += 256) {
    int r = i / 24, c4 = i - r * 24;
    float4 e = make_float4(0.f, 0.f, 0.f, 0.f), s = e;
    if (nbase + r < NN) {
      e = ((const float4*)(ego + (size_t)(nbase + r) * DD))[c4];
      s = ((const float4*)(side + (size_t)(nbase + r) * DD))[c4];
    }
    short4v xv, yv;
    xv.x = (short)f2bf(e.x + s.x); xv.y = (short)f2bf(e.y + s.y);
    xv.z = (short)f2bf(e.z + s.z); xv.w = (short)f2bf(e.w + s.w);
    yv.x = (short)f2bf(e.x * s.x); yv.y = (short)f2bf(e.y * s.y);
    yv.z = (short)f2bf(e.z * s.z); yv.w = (short)f2bf(e.w * s.w);
    *(short4v*)(xs + r * XST + c4 * 4) = xv;
    *(short4v*)(ys + r * XST + c4 * 4) = yv;
  }
  __syncthreads();

  int w = tid >> 6, l = tid & 63;
  int lrow = l & 15, lk = l >> 4;

  f32x4 acc1[6], acc2[6];
#pragma unroll
  for (int t = 0; t < 6; ++t) {
    acc1[t] = (f32x4){0.f, 0.f, 0.f, 0.f};
    acc2[t] = (f32x4){0.f, 0.f, 0.f, 0.f};
  }

  const unsigned short* xrow = xs + (w * 16 + lrow) * XST + lk * 8;
  const unsigned short* yrow = ys + (w * 16 + lrow) * XST + lk * 8;

#pragma unroll
  for (int kk = 0; kk < 3; ++kk) {
    short8v ax = *(const short8v*)(xrow + kk * 32);
    short8v ay = *(const short8v*)(yrow + kk * 32);
    int kb = kk * 32 + lk * 8;
#pragma unroll
    for (int t = 0; t < 6; ++t) {
      int j = t * 16 + lrow;
      short8v bw1 = *(const short8v*)(Wb1 + j * DD + kb);
      short8v bw2 = *(const short8v*)(Wb2 + j * DD + kb);
      acc1[t] = __builtin_amdgcn_mfma_f32_16x16x32_bf16(ax, bw1, acc1[t], 0, 0, 0);
      acc2[t] = __builtin_amdgcn_mfma_f32_16x16x32_bf16(ay, bw2, acc2[t], 0, 0, 0);
    }
  }

  int node0 = nbase + w * 16 + lk * 4;
#pragma unroll
  for (int t = 0; t < 6; ++t) {
    int j = t * 16 + lrow;
    float bb1 = b1[j], bb2 = b2[j];
#pragma unroll
    for (int i = 0; i < 4; ++i) {
      int node = node0 + i;
      if (node < NN)
        out[(size_t)node * DD + j] = lrelu(acc1[t][i] + bb1) + lrelu(acc2[t][i] + bb2);
    }
  }
}

// ================= launch =================
extern "C" void kernel_launch(void* const* d_in, const int* in_sizes, int n_in,
                              void* d_out, int out_size, void* d_ws, size_t ws_size,
                              hipStream_t stream) {
  const float* ego   = (const float*)d_in[0];
  const float* avals = (const float*)d_in[1];
  const float* W1    = (const float*)d_in[2];
  const float* b1    = (const float*)d_in[3];
  const float* W2    = (const float*)d_in[4];
  const float* b2    = (const float*)d_in[5];
  const int* arows   = (const int*)d_in[6];
  const int* acols   = (const int*)d_in[7];
  float* out = (float*)d_out;

  size_t off = 0;
  auto bump = [&](size_t bytes) {
    size_t o = off;
    off += (bytes + 1023) & ~(size_t)1023;
    return o;
  };
  char* ws = (char*)d_ws;
  size_t o_head = bump((size_t)NN * 4);
  size_t o_nxt  = bump((size_t)NE * 4);
  size_t o_wb1  = bump((size_t)DD * DD * 2);
  size_t o_wb2  = bump((size_t)DD * DD * 2);
  size_t o_egob = bump((size_t)NN * DD * 2);
  size_t o_side = bump((size_t)NN * DD * 4);
  size_t need = off;

  if (ws_size >= need) {
    int*   head = (int*)(ws + o_head);
    int*   nxt  = (int*)(ws + o_nxt);
    unsigned short* Wb1  = (unsigned short*)(ws + o_wb1);
    unsigned short* Wb2  = (unsigned short*)(ws + o_wb2);
    unsigned short* egob = (unsigned short*)(ws + o_egob);
    float* side = (float*)(ws + o_side);

    hipMemsetAsync(head, 0xFF, (size_t)NN * 4, stream);  // head = -1
    prep_kernel<<<NB_CNT + NB_W + NB_E, 256, 0, stream>>>(
        arows, head, nxt, W1, W2, Wb1, Wb2, ego, egob);
    agg5_kernel<<<(NN + 127) / 128, 128, 0, stream>>>(
        egob, head, nxt, acols, avals, side);
    fuse4_kernel<<<(NN + FN - 1) / FN, 256, 0, stream>>>(
        ego, side, Wb1, Wb2, b1, b2, out);
  } else {
    size_t side_bytes = (size_t)NN * DD * sizeof(float);
    float* side = (ws_size >= side_bytes) ? (float*)d_ws : out;
    hipMemsetAsync(side, 0, side_bytes, stream);
    long long nthreads = (long long)NE * 32;
    int blocks = (int)((nthreads + 255) / 256);
    scatter_kernel<<<blocks, 256, 0, stream>>>(ego, avals, arows, acols, side);
    fuse_fb_kernel<<<1024, 192, 0, stream>>>(ego, side, W1, b1, W2, b2, out);
  }
}

// Round 8
// 161.234 us; speedup vs baseline: 2.8785x; 2.8785x over previous
//
#include <hip/hip_runtime.h>

#define NN 50000
#define NE 800000
#define DD 96
#define NEG 0.01f
#define NB 196      // scan blocks: 196*256 = 50176 >= NN
#define FN 64       // nodes per fuse4 block
#define XST 104     // LDS row stride (bf16 units): 208 B, 16B-aligned

typedef __attribute__((ext_vector_type(8))) short short8v;
typedef __attribute__((ext_vector_type(4))) short short4v;
typedef __attribute__((ext_vector_type(4))) float f32x4;

static __device__ __forceinline__ float lrelu(float x) {
  return (x >= 0.f) ? x : NEG * x;
}
static __device__ __forceinline__ void fma4(float4& a, float v, const float4& x) {
  a.x += v * x.x; a.y += v * x.y; a.z += v * x.z; a.w += v * x.w;
}
static __device__ __forceinline__ unsigned short f2bf(float x) {
  unsigned u = __float_as_uint(x);
  u += 0x7fffu + ((u >> 16) & 1u);   // RNE
  return (unsigned short)(u >> 16);
}
static __device__ __forceinline__ float bf2f(unsigned short h) {
  return __uint_as_float(((unsigned)h) << 16);
}

// ================= fallback (round-1) path =================
__global__ __launch_bounds__(256) void scatter_kernel(
    const float* __restrict__ ego, const float* __restrict__ avals,
    const int* __restrict__ arows, const int* __restrict__ acols,
    float* __restrict__ side)
{
  int t = blockIdx.x * 256 + threadIdx.x;
  int e = t >> 5;
  int lane = t & 31;
  if (e >= NE) return;
  int row = arows[e];
  int col = acols[e];
  float v = avals[e];
  if (lane < 24) {
    const float4* src = (const float4*)(ego + (size_t)col * DD);
    float4 x = src[lane];
    float* dst = side + (size_t)row * DD + lane * 4;
    unsafeAtomicAdd(dst + 0, v * x.x);
    unsafeAtomicAdd(dst + 1, v * x.y);
    unsafeAtomicAdd(dst + 2, v * x.z);
    unsafeAtomicAdd(dst + 3, v * x.w);
  }
}

__global__ __launch_bounds__(192) void fuse_fb_kernel(
    const float* __restrict__ ego, const float* __restrict__ side,
    const float* __restrict__ W1, const float* __restrict__ b1,
    const float* __restrict__ W2, const float* __restrict__ b2,
    float* __restrict__ out)
{
  __shared__ float W1t[DD * DD];
  __shared__ float W2t[DD * DD];
  __shared__ float b1s[DD], b2s[DD];
  __shared__ float xs[192], ys[192];
  int tid = threadIdx.x;
  for (int i = tid; i < DD * DD; i += 192) {
    int j = i / DD, k = i - j * DD;
    W1t[k * DD + j] = W1[i];
    W2t[k * DD + j] = W2[i];
  }
  if (tid < DD) { b1s[tid] = b1[tid]; b2s[tid] = b2[tid]; }
  __syncthreads();
  int nl = tid / DD, j = tid - nl * DD;
  for (int p = blockIdx.x; p < NN / 2; p += gridDim.x) {
    int base = p * 192;
    float e = ego[base + tid], s = side[base + tid];
    xs[tid] = e + s; ys[tid] = e * s;
    __syncthreads();
    float a1 = b1s[j], a2 = b2s[j];
    const float* xr = xs + nl * DD;
    const float* yr = ys + nl * DD;
#pragma unroll 16
    for (int k = 0; k < DD; ++k) {
      a1 += xr[k] * W1t[k * DD + j];
      a2 += yr[k] * W2t[k * DD + j];
    }
    float r = lrelu(a1) + lrelu(a2);
    __syncthreads();
    out[base + tid] = r;
  }
}

// ========== prep: edge count + W->bf16 + ego->bf16 (one dispatch) ==========
#define NB_CNT (NE / 256)          // 3125
#define NB_W   ((DD * DD) / 256)   // 36
#define NE4    (NN * DD / 4)       // 1200000 float4 units
#define NB_E   ((NE4 + 255) / 256) // 4688
__global__ __launch_bounds__(256) void prep_kernel(
    const int* __restrict__ rows, int* __restrict__ cnt,
    const float* __restrict__ W1, const float* __restrict__ W2,
    unsigned short* __restrict__ Wb1, unsigned short* __restrict__ Wb2,
    const float* __restrict__ ego, unsigned short* __restrict__ egob)
{
  int b = blockIdx.x;
  if (b < NB_CNT) {
    atomicAdd(&cnt[rows[b * 256 + threadIdx.x]], 1);
  } else if (b < NB_CNT + NB_W) {
    int i = (b - NB_CNT) * 256 + threadIdx.x;  // [0, 9216)
    Wb1[i] = f2bf(W1[i]);
    Wb2[i] = f2bf(W2[i]);
  } else {
    int i = (b - NB_CNT - NB_W) * 256 + threadIdx.x;
    if (i < NE4) {
      float4 v = ((const float4*)ego)[i];
      short4v o;
      o.x = (short)f2bf(v.x); o.y = (short)f2bf(v.y);
      o.z = (short)f2bf(v.z); o.w = (short)f2bf(v.w);
      ((short4v*)egob)[i] = o;
    }
  }
}

// ================= 3-kernel parallel exclusive scan =================
__global__ __launch_bounds__(256) void scan1_kernel(const int* __restrict__ cnt,
                                                    int* __restrict__ bsum) {
  __shared__ int s[256];
  int t = threadIdx.x, i = blockIdx.x * 256 + t;
  s[t] = (i < NN) ? cnt[i] : 0;
  __syncthreads();
  for (int off = 128; off > 0; off >>= 1) {
    if (t < off) s[t] += s[t + off];
    __syncthreads();
  }
  if (t == 0) bsum[blockIdx.x] = s[0];
}

__global__ __launch_bounds__(256) void scan2_kernel(const int* __restrict__ bsum,
                                                    int* __restrict__ bexcl) {
  __shared__ int s[256];
  int t = threadIdx.x;
  int v = (t < NB) ? bsum[t] : 0;
  s[t] = v;
  __syncthreads();
  for (int off = 1; off < 256; off <<= 1) {
    int add = (t >= off) ? s[t - off] : 0;
    __syncthreads();
    s[t] += add;
    __syncthreads();
  }
  if (t < NB) bexcl[t] = s[t] - v;
}

__global__ __launch_bounds__(256) void scan3_kernel(const int* __restrict__ cnt,
                                                    const int* __restrict__ bexcl,
                                                    int* __restrict__ row_start,
                                                    int* __restrict__ wptr) {
  __shared__ int s[256];
  int t = threadIdx.x, i = blockIdx.x * 256 + t;
  int v = (i < NN) ? cnt[i] : 0;
  s[t] = v;
  __syncthreads();
  for (int off = 1; off < 256; off <<= 1) {
    int add = (t >= off) ? s[t - off] : 0;
    __syncthreads();
    s[t] += add;
    __syncthreads();
  }
  int rs = bexcl[blockIdx.x] + s[t] - v;
  if (i < NN) { row_start[i] = rs; wptr[i] = rs; }
  if (i == NN) row_start[NN] = NE;
}

// fill: 4-byte packed entries (col:16 | val_bf16:16) -> halves the
// scattered-store payload (partial-line writeback amplification ~ bytes)
__global__ __launch_bounds__(256) void fill_kernel(
    const int* __restrict__ rows, const int* __restrict__ cols,
    const float* __restrict__ vals, int* __restrict__ wptr,
    unsigned* __restrict__ cv) {
  int e = blockIdx.x * 256 + threadIdx.x;  // grid exactly NE/256
  int r = rows[e];
  int p = atomicAdd(&wptr[r], 1);
  cv[p] = (unsigned)cols[e] | ((unsigned)f2bf(vals[e]) << 16);
}

// ====== segment reduction: wave/row, bf16 gathers, 16 edges in flight ======
__global__ __launch_bounds__(256) void agg_kernel(
    const unsigned short* __restrict__ egob, const int* __restrict__ row_start,
    const unsigned* __restrict__ cv, float* __restrict__ side) {
  int wid = threadIdx.x >> 6, lane = threadIdx.x & 63;
  int row = blockIdx.x * 4 + wid;
  if (row >= NN) return;
  int s = row_start[row], e = row_start[row + 1];
  int half = lane >> 5, hl = lane & 31;
  float4 a[8];
#pragma unroll
  for (int d = 0; d < 8; ++d) a[d] = make_float4(0.f, 0.f, 0.f, 0.f);

  for (int base = s; base < e; base += 64) {
    int idx = base + lane;
    unsigned pk = 0;                      // col=0, val=+0.0 -> contributes 0
    if (idx < e) pk = cv[idx];
    int n = min(64, e - base);
    for (int i = 0; i < n; i += 16) {
#pragma unroll
      for (int d = 0; d < 8; ++d) {
        unsigned p = __shfl(pk, i + 2 * d + half, 64);
        int c = (int)(p & 0xFFFFu);
        float v = bf2f((unsigned short)(p >> 16));
        if (hl < 24) {
          short4v x = ((const short4v*)(egob + (size_t)c * DD))[hl];
          float4 xf = make_float4(bf2f((unsigned short)x.x),
                                  bf2f((unsigned short)x.y),
                                  bf2f((unsigned short)x.z),
                                  bf2f((unsigned short)x.w));
          fma4(a[d], v, xf);
        }
      }
    }
  }
  float4 acc;
  acc.x = ((a[0].x + a[1].x) + (a[2].x + a[3].x)) + ((a[4].x + a[5].x) + (a[6].x + a[7].x));
  acc.y = ((a[0].y + a[1].y) + (a[2].y + a[3].y)) + ((a[4].y + a[5].y) + (a[6].y + a[7].y));
  acc.z = ((a[0].z + a[1].z) + (a[2].z + a[3].z)) + ((a[4].z + a[5].z) + (a[6].z + a[7].z));
  acc.w = ((a[0].w + a[1].w) + (a[2].w + a[3].w)) + ((a[4].w + a[5].w) + (a[6].w + a[7].w));
  acc.x += __shfl(acc.x, lane ^ 32, 64);
  acc.y += __shfl(acc.y, lane ^ 32, 64);
  acc.z += __shfl(acc.z, lane ^ 32, 64);
  acc.w += __shfl(acc.w, lane ^ 32, 64);
  if (half == 0 && hl < 24)
    *((float4*)(side + (size_t)row * DD) + hl) = acc;
}

// ========== fused bi-interaction via bf16 MFMA (verified) ==========
__global__ __launch_bounds__(256) void fuse4_kernel(
    const float* __restrict__ ego, const float* __restrict__ side,
    const unsigned short* __restrict__ Wb1, const unsigned short* __restrict__ Wb2,
    const float* __restrict__ b1, const float* __restrict__ b2,
    float* __restrict__ out)
{
  __shared__ unsigned short xs[FN * XST];
  __shared__ unsigned short ys[FN * XST];
  int tid = threadIdx.x;
  int nbase = blockIdx.x * FN;

  for (int i = tid; i < FN * 24; i += 256) {
    int r = i / 24, c4 = i - r * 24;
    float4 e = make_float4(0.f, 0.f, 0.f, 0.f), s = e;
    if (nbase + r < NN) {
      e = ((const float4*)(ego + (size_t)(nbase + r) * DD))[c4];
      s = ((const float4*)(side + (size_t)(nbase + r) * DD))[c4];
    }
    short4v xv, yv;
    xv.x = (short)f2bf(e.x + s.x); xv.y = (short)f2bf(e.y + s.y);
    xv.z = (short)f2bf(e.z + s.z); xv.w = (short)f2bf(e.w + s.w);
    yv.x = (short)f2bf(e.x * s.x); yv.y = (short)f2bf(e.y * s.y);
    yv.z = (short)f2bf(e.z * s.z); yv.w = (short)f2bf(e.w * s.w);
    *(short4v*)(xs + r * XST + c4 * 4) = xv;
    *(short4v*)(ys + r * XST + c4 * 4) = yv;
  }
  __syncthreads();

  int w = tid >> 6, l = tid & 63;
  int lrow = l & 15, lk = l >> 4;

  f32x4 acc1[6], acc2[6];
#pragma unroll
  for (int t = 0; t < 6; ++t) {
    acc1[t] = (f32x4){0.f, 0.f, 0.f, 0.f};
    acc2[t] = (f32x4){0.f, 0.f, 0.f, 0.f};
  }

  const unsigned short* xrow = xs + (w * 16 + lrow) * XST + lk * 8;
  const unsigned short* yrow = ys + (w * 16 + lrow) * XST + lk * 8;

#pragma unroll
  for (int kk = 0; kk < 3; ++kk) {
    short8v ax = *(const short8v*)(xrow + kk * 32);
    short8v ay = *(const short8v*)(yrow + kk * 32);
    int kb = kk * 32 + lk * 8;
#pragma unroll
    for (int t = 0; t < 6; ++t) {
      int j = t * 16 + lrow;
      short8v bw1 = *(const short8v*)(Wb1 + j * DD + kb);
      short8v bw2 = *(const short8v*)(Wb2 + j * DD + kb);
      acc1[t] = __builtin_amdgcn_mfma_f32_16x16x32_bf16(ax, bw1, acc1[t], 0, 0, 0);
      acc2[t] = __builtin_amdgcn_mfma_f32_16x16x32_bf16(ay, bw2, acc2[t], 0, 0, 0);
    }
  }

  int node0 = nbase + w * 16 + lk * 4;
#pragma unroll
  for (int t = 0; t < 6; ++t) {
    int j = t * 16 + lrow;
    float bb1 = b1[j], bb2 = b2[j];
#pragma unroll
    for (int i = 0; i < 4; ++i) {
      int node = node0 + i;
      if (node < NN)
        out[(size_t)node * DD + j] = lrelu(acc1[t][i] + bb1) + lrelu(acc2[t][i] + bb2);
    }
  }
}

// ================= launch =================
extern "C" void kernel_launch(void* const* d_in, const int* in_sizes, int n_in,
                              void* d_out, int out_size, void* d_ws, size_t ws_size,
                              hipStream_t stream) {
  const float* ego   = (const float*)d_in[0];
  const float* avals = (const float*)d_in[1];
  const float* W1    = (const float*)d_in[2];
  const float* b1    = (const float*)d_in[3];
  const float* W2    = (const float*)d_in[4];
  const float* b2    = (const float*)d_in[5];
  const int* arows   = (const int*)d_in[6];
  const int* acols   = (const int*)d_in[7];
  float* out = (float*)d_out;

  size_t off = 0;
  auto bump = [&](size_t bytes) {
    size_t o = off;
    off += (bytes + 1023) & ~(size_t)1023;
    return o;
  };
  char* ws = (char*)d_ws;
  size_t o_cnt  = bump((size_t)NN * 4);
  size_t o_rs   = bump((size_t)(NN + 1) * 4);
  size_t o_wp   = bump((size_t)NN * 4);
  size_t o_bs   = bump((size_t)NB * 4);
  size_t o_be   = bump((size_t)NB * 4);
  size_t o_cv   = bump((size_t)NE * 4);
  size_t o_wb1  = bump((size_t)DD * DD * 2);
  size_t o_wb2  = bump((size_t)DD * DD * 2);
  size_t o_egob = bump((size_t)NN * DD * 2);
  size_t o_side = bump((size_t)NN * DD * 4);
  size_t need = off;

  if (ws_size >= need) {
    int*   cnt  = (int*)(ws + o_cnt);
    int*   rs   = (int*)(ws + o_rs);
    int*   wp   = (int*)(ws + o_wp);
    int*   bs   = (int*)(ws + o_bs);
    int*   be   = (int*)(ws + o_be);
    unsigned* cv = (unsigned*)(ws + o_cv);
    unsigned short* Wb1  = (unsigned short*)(ws + o_wb1);
    unsigned short* Wb2  = (unsigned short*)(ws + o_wb2);
    unsigned short* egob = (unsigned short*)(ws + o_egob);
    float* side = (float*)(ws + o_side);

    hipMemsetAsync(cnt, 0, (size_t)NN * 4, stream);
    prep_kernel<<<NB_CNT + NB_W + NB_E, 256, 0, stream>>>(
        arows, cnt, W1, W2, Wb1, Wb2, ego, egob);
    scan1_kernel<<<NB, 256, 0, stream>>>(cnt, bs);
    scan2_kernel<<<1, 256, 0, stream>>>(bs, be);
    scan3_kernel<<<NB, 256, 0, stream>>>(cnt, be, rs, wp);
    fill_kernel<<<NE / 256, 256, 0, stream>>>(arows, acols, avals, wp, cv);
    agg_kernel<<<(NN + 3) / 4, 256, 0, stream>>>(egob, rs, cv, side);
    fuse4_kernel<<<(NN + FN - 1) / FN, 256, 0, stream>>>(
        ego, side, Wb1, Wb2, b1, b2, out);
  } else {
    size_t side_bytes = (size_t)NN * DD * sizeof(float);
    float* side = (ws_size >= side_bytes) ? (float*)d_ws : out;
    hipMemsetAsync(side, 0, side_bytes, stream);
    long long nthreads = (long long)NE * 32;
    int blocks = (int)((nthreads + 255) / 256);
    scatter_kernel<<<blocks, 256, 0, stream>>>(ego, avals, arows, acols, side);
    fuse_fb_kernel<<<1024, 192, 0, stream>>>(ego, side, W1, b1, W2, b2, out);
  }
}

// Round 9
// 109.351 us; speedup vs baseline: 4.2442x; 1.4745x over previous
//
#include <hip/hip_runtime.h>

#define NN 50000
#define NE 800000
#define DD 96
#define NEG 0.01f
#define FN 64        // nodes per fuse4 block
#define XST 104      // LDS row stride (bf16 units)
#define NBK 196      // buckets = row>>8 (256 rows each)
#define BCAP 12000   // bucket region capacity (mean 4082; overflow list beyond)
#define EPA 4096     // edges per binA block
#define NA 196       // binA blocks: 196*4096 = 802816 >= NE
#define OVCAP 65536  // overflow list capacity (normally 0 used)

typedef __attribute__((ext_vector_type(8))) short short8v;
typedef __attribute__((ext_vector_type(4))) short short4v;
typedef __attribute__((ext_vector_type(4))) float f32x4;

static __device__ __forceinline__ float lrelu(float x) {
  return (x >= 0.f) ? x : NEG * x;
}
static __device__ __forceinline__ void fma4(float4& a, float v, const float4& x) {
  a.x += v * x.x; a.y += v * x.y; a.z += v * x.z; a.w += v * x.w;
}
static __device__ __forceinline__ unsigned short f2bf(float x) {
  unsigned u = __float_as_uint(x);
  u += 0x7fffu + ((u >> 16) & 1u);   // RNE
  return (unsigned short)(u >> 16);
}
static __device__ __forceinline__ float bf2f(unsigned short h) {
  return __uint_as_float(((unsigned)h) << 16);
}

// ================= fallback (round-1) path =================
__global__ __launch_bounds__(256) void scatter_kernel(
    const float* __restrict__ ego, const float* __restrict__ avals,
    const int* __restrict__ arows, const int* __restrict__ acols,
    float* __restrict__ side)
{
  int t = blockIdx.x * 256 + threadIdx.x;
  int e = t >> 5;
  int lane = t & 31;
  if (e >= NE) return;
  int row = arows[e];
  int col = acols[e];
  float v = avals[e];
  if (lane < 24) {
    const float4* src = (const float4*)(ego + (size_t)col * DD);
    float4 x = src[lane];
    float* dst = side + (size_t)row * DD + lane * 4;
    unsafeAtomicAdd(dst + 0, v * x.x);
    unsafeAtomicAdd(dst + 1, v * x.y);
    unsafeAtomicAdd(dst + 2, v * x.z);
    unsafeAtomicAdd(dst + 3, v * x.w);
  }
}

__global__ __launch_bounds__(192) void fuse_fb_kernel(
    const float* __restrict__ ego, const float* __restrict__ side,
    const float* __restrict__ W1, const float* __restrict__ b1,
    const float* __restrict__ W2, const float* __restrict__ b2,
    float* __restrict__ out)
{
  __shared__ float W1t[DD * DD];
  __shared__ float W2t[DD * DD];
  __shared__ float b1s[DD], b2s[DD];
  __shared__ float xs[192], ys[192];
  int tid = threadIdx.x;
  for (int i = tid; i < DD * DD; i += 192) {
    int j = i / DD, k = i - j * DD;
    W1t[k * DD + j] = W1[i];
    W2t[k * DD + j] = W2[i];
  }
  if (tid < DD) { b1s[tid] = b1[tid]; b2s[tid] = b2[tid]; }
  __syncthreads();
  int nl = tid / DD, j = tid - nl * DD;
  for (int p = blockIdx.x; p < NN / 2; p += gridDim.x) {
    int base = p * 192;
    float e = ego[base + tid], s = side[base + tid];
    xs[tid] = e + s; ys[tid] = e * s;
    __syncthreads();
    float a1 = b1s[j], a2 = b2s[j];
    const float* xr = xs + nl * DD;
    const float* yr = ys + nl * DD;
#pragma unroll 16
    for (int k = 0; k < DD; ++k) {
      a1 += xr[k] * W1t[k * DD + j];
      a2 += yr[k] * W2t[k * DD + j];
    }
    float r = lrelu(a1) + lrelu(a2);
    __syncthreads();
    out[base + tid] = r;
  }
}

// ========== prep_conv: W->bf16 + ego->bf16 ==========
#define NB_W   ((DD * DD) / 256)   // 36
#define NE4    (NN * DD / 4)       // 1200000 float4 units
#define NB_E   ((NE4 + 255) / 256) // 4688
__global__ __launch_bounds__(256) void prep_conv_kernel(
    const float* __restrict__ W1, const float* __restrict__ W2,
    unsigned short* __restrict__ Wb1, unsigned short* __restrict__ Wb2,
    const float* __restrict__ ego, unsigned short* __restrict__ egob)
{
  int b = blockIdx.x;
  if (b < NB_W) {
    int i = b * 256 + threadIdx.x;  // [0, 9216)
    Wb1[i] = f2bf(W1[i]);
    Wb2[i] = f2bf(W2[i]);
  } else {
    int i = (b - NB_W) * 256 + threadIdx.x;
    if (i < NE4) {
      float4 v = ((const float4*)ego)[i];
      short4v o;
      o.x = (short)f2bf(v.x); o.y = (short)f2bf(v.y);
      o.z = (short)f2bf(v.z); o.w = (short)f2bf(v.w);
      ((short4v*)egob)[i] = o;
    }
  }
}

// ========== binA: LDS-staged bucket binning (coalesced chunk flush) ==========
// entry: w0 = col | (row&255)<<16 | bucket<<24 ; w1 = bf16(val)
__global__ __launch_bounds__(256) void binA_kernel(
    const int* __restrict__ rows, const int* __restrict__ cols,
    const float* __restrict__ vals,
    int* __restrict__ bptr, int* __restrict__ ovcur,
    int2* __restrict__ ovbuf, int2* __restrict__ buckets)
{
  __shared__ unsigned sw0[EPA];
  __shared__ unsigned sw1[EPA];
  __shared__ unsigned char sbid[EPA];
  __shared__ int bcnt[256], bofs[256], gbase[256], stmp[256];

  int tid = threadIdx.x;
  int base = blockIdx.x * EPA;
  int cnt_here = min(EPA, NE - base);

  bcnt[tid] = 0;
  __syncthreads();

  unsigned w0[16], w1[16];
  int bb[16], lp[16];
#pragma unroll
  for (int k = 0; k < 16; ++k) {
    int i = tid + k * 256;
    bb[k] = -1;
    if (i < cnt_here) {
      int e = base + i;
      int r = rows[e], c = cols[e];
      float v = vals[e];
      int b = r >> 8;
      bb[k] = b;
      w0[k] = (unsigned)c | ((unsigned)(r & 255) << 16) | ((unsigned)b << 24);
      w1[k] = (unsigned)f2bf(v);
      lp[k] = atomicAdd(&bcnt[b], 1);
    }
  }
  __syncthreads();

  int v = bcnt[tid];
  stmp[tid] = v;
  __syncthreads();
  for (int off = 1; off < 256; off <<= 1) {
    int add = (tid >= off) ? stmp[tid - off] : 0;
    __syncthreads();
    stmp[tid] += add;
    __syncthreads();
  }
  bofs[tid] = stmp[tid] - v;  // exclusive
  gbase[tid] = (tid < NBK && v > 0) ? atomicAdd(&bptr[tid], v) : 0;
  __syncthreads();

#pragma unroll
  for (int k = 0; k < 16; ++k) {
    if (bb[k] >= 0) {
      int s = bofs[bb[k]] + lp[k];
      sw0[s] = w0[k];
      sw1[s] = w1[k];
      sbid[s] = (unsigned char)bb[k];
    }
  }
  __syncthreads();

  for (int i = tid; i < cnt_here; i += 256) {
    int b = sbid[i];
    int off = i - bofs[b];
    int g = gbase[b] + off;
    int2 ent = make_int2((int)sw0[i], (int)sw1[i]);
    if (g < BCAP) {
      buckets[(size_t)b * BCAP + g] = ent;
    } else {
      int op = atomicAdd(ovcur, 1);
      if (op < OVCAP) ovbuf[op] = ent;
    }
  }
}

// ========== scanb: exclusive scan of 196 bucket totals (1 block) ==========
__global__ __launch_bounds__(256) void scanb_kernel(const int* __restrict__ bptr,
                                                    int* __restrict__ sbase) {
  __shared__ int s[256];
  int t = threadIdx.x;
  int v = (t < NBK) ? bptr[t] : 0;
  s[t] = v;
  __syncthreads();
  for (int off = 1; off < 256; off <<= 1) {
    int add = (t >= off) ? s[t - off] : 0;
    __syncthreads();
    s[t] += add;
    __syncthreads();
  }
  if (t == 0) sbase[0] = 0;
  if (t < NBK) sbase[t + 1] = s[t];  // inclusive -> sbase[b+1]
}

// ========== binB: per-bucket counting sort -> cv + row_start ==========
__global__ __launch_bounds__(256) void binB_kernel(
    const int2* __restrict__ buckets, const int* __restrict__ bptr,
    const int* __restrict__ sbase, const int* __restrict__ ovcur,
    const int2* __restrict__ ovbuf,
    unsigned* __restrict__ cv, int* __restrict__ row_start)
{
  __shared__ int rcnt[256], rofs[256], rcur[256], stmp[256];
  int b = blockIdx.x, tid = threadIdx.x;
  int total = bptr[b];
  int nreg = min(total, BCAP);
  int nov = min(*ovcur, OVCAP);
  int cvb = sbase[b];
  const int2* reg = buckets + (size_t)b * BCAP;

  rcnt[tid] = 0;
  __syncthreads();

  for (int i = tid; i < nreg; i += 256) {
    unsigned w0 = (unsigned)reg[i].x;
    atomicAdd(&rcnt[(w0 >> 16) & 255], 1);
  }
  for (int i = tid; i < nov; i += 256) {
    unsigned w0 = (unsigned)ovbuf[i].x;
    if ((w0 >> 24) == (unsigned)b) atomicAdd(&rcnt[(w0 >> 16) & 255], 1);
  }
  __syncthreads();

  int v = rcnt[tid];
  stmp[tid] = v;
  __syncthreads();
  for (int off = 1; off < 256; off <<= 1) {
    int add = (tid >= off) ? stmp[tid - off] : 0;
    __syncthreads();
    stmp[tid] += add;
    __syncthreads();
  }
  rofs[tid] = stmp[tid] - v;  // exclusive within bucket
  rcur[tid] = rofs[tid];
  int grow = b * 256 + tid;
  if (grow <= NN) row_start[grow] = cvb + rofs[tid];
  __syncthreads();

  for (int i = tid; i < nreg; i += 256) {
    unsigned w0 = (unsigned)reg[i].x;
    unsigned w1 = (unsigned)reg[i].y;
    int rl = (w0 >> 16) & 255;
    int p = atomicAdd(&rcur[rl], 1);
    cv[cvb + p] = (w0 & 0xFFFFu) | (w1 << 16);
  }
  for (int i = tid; i < nov; i += 256) {
    unsigned w0 = (unsigned)ovbuf[i].x;
    unsigned w1 = (unsigned)ovbuf[i].y;
    if ((w0 >> 24) == (unsigned)b) {
      int rl = (w0 >> 16) & 255;
      int p = atomicAdd(&rcur[rl], 1);
      cv[cvb + p] = (w0 & 0xFFFFu) | (w1 << 16);
    }
  }
}

// ====== segment reduction: wave/row, bf16 gathers (verified R8) ======
__global__ __launch_bounds__(256) void agg_kernel(
    const unsigned short* __restrict__ egob, const int* __restrict__ row_start,
    const unsigned* __restrict__ cv, float* __restrict__ side) {
  int wid = threadIdx.x >> 6, lane = threadIdx.x & 63;
  int row = blockIdx.x * 4 + wid;
  if (row >= NN) return;
  int s = row_start[row], e = row_start[row + 1];
  int half = lane >> 5, hl = lane & 31;
  float4 a[8];
#pragma unroll
  for (int d = 0; d < 8; ++d) a[d] = make_float4(0.f, 0.f, 0.f, 0.f);

  for (int base = s; base < e; base += 64) {
    int idx = base + lane;
    unsigned pk = 0;
    if (idx < e) pk = cv[idx];
    int n = min(64, e - base);
    for (int i = 0; i < n; i += 16) {
#pragma unroll
      for (int d = 0; d < 8; ++d) {
        unsigned p = __shfl(pk, i + 2 * d + half, 64);
        int c = (int)(p & 0xFFFFu);
        float v = bf2f((unsigned short)(p >> 16));
        if (hl < 24) {
          short4v x = ((const short4v*)(egob + (size_t)c * DD))[hl];
          float4 xf = make_float4(bf2f((unsigned short)x.x),
                                  bf2f((unsigned short)x.y),
                                  bf2f((unsigned short)x.z),
                                  bf2f((unsigned short)x.w));
          fma4(a[d], v, xf);
        }
      }
    }
  }
  float4 acc;
  acc.x = ((a[0].x + a[1].x) + (a[2].x + a[3].x)) + ((a[4].x + a[5].x) + (a[6].x + a[7].x));
  acc.y = ((a[0].y + a[1].y) + (a[2].y + a[3].y)) + ((a[4].y + a[5].y) + (a[6].y + a[7].y));
  acc.z = ((a[0].z + a[1].z) + (a[2].z + a[3].z)) + ((a[4].z + a[5].z) + (a[6].z + a[7].z));
  acc.w = ((a[0].w + a[1].w) + (a[2].w + a[3].w)) + ((a[4].w + a[5].w) + (a[6].w + a[7].w));
  acc.x += __shfl(acc.x, lane ^ 32, 64);
  acc.y += __shfl(acc.y, lane ^ 32, 64);
  acc.z += __shfl(acc.z, lane ^ 32, 64);
  acc.w += __shfl(acc.w, lane ^ 32, 64);
  if (half == 0 && hl < 24)
    *((float4*)(side + (size_t)row * DD) + hl) = acc;
}

// ========== fused bi-interaction via bf16 MFMA (verified) ==========
__global__ __launch_bounds__(256) void fuse4_kernel(
    const float* __restrict__ ego, const float* __restrict__ side,
    const unsigned short* __restrict__ Wb1, const unsigned short* __restrict__ Wb2,
    const float* __restrict__ b1, const float* __restrict__ b2,
    float* __restrict__ out)
{
  __shared__ unsigned short xs[FN * XST];
  __shared__ unsigned short ys[FN * XST];
  int tid = threadIdx.x;
  int nbase = blockIdx.x * FN;

  for (int i = tid; i < FN * 24; i += 256) {
    int r = i / 24, c4 = i - r * 24;
    float4 e = make_float4(0.f, 0.f, 0.f, 0.f), s = e;
    if (nbase + r < NN) {
      e = ((const float4*)(ego + (size_t)(nbase + r) * DD))[c4];
      s = ((const float4*)(side + (size_t)(nbase + r) * DD))[c4];
    }
    short4v xv, yv;
    xv.x = (short)f2bf(e.x + s.x); xv.y = (short)f2bf(e.y + s.y);
    xv.z = (short)f2bf(e.z + s.z); xv.w = (short)f2bf(e.w + s.w);
    yv.x = (short)f2bf(e.x * s.x); yv.y = (short)f2bf(e.y * s.y);
    yv.z = (short)f2bf(e.z * s.z); yv.w = (short)f2bf(e.w * s.w);
    *(short4v*)(xs + r * XST + c4 * 4) = xv;
    *(short4v*)(ys + r * XST + c4 * 4) = yv;
  }
  __syncthreads();

  int w = tid >> 6, l = tid & 63;
  int lrow = l & 15, lk = l >> 4;

  f32x4 acc1[6], acc2[6];
#pragma unroll
  for (int t = 0; t < 6; ++t) {
    acc1[t] = (f32x4){0.f, 0.f, 0.f, 0.f};
    acc2[t] = (f32x4){0.f, 0.f, 0.f, 0.f};
  }

  const unsigned short* xrow = xs + (w * 16 + lrow) * XST + lk * 8;
  const unsigned short* yrow = ys + (w * 16 + lrow) * XST + lk * 8;

#pragma unroll
  for (int kk = 0; kk < 3; ++kk) {
    short8v ax = *(const short8v*)(xrow + kk * 32);
    short8v ay = *(const short8v*)(yrow + kk * 32);
    int kb = kk * 32 + lk * 8;
#pragma unroll
    for (int t = 0; t < 6; ++t) {
      int j = t * 16 + lrow;
      short8v bw1 = *(const short8v*)(Wb1 + j * DD + kb);
      short8v bw2 = *(const short8v*)(Wb2 + j * DD + kb);
      acc1[t] = __builtin_amdgcn_mfma_f32_16x16x32_bf16(ax, bw1, acc1[t], 0, 0, 0);
      acc2[t] = __builtin_amdgcn_mfma_f32_16x16x32_bf16(ay, bw2, acc2[t], 0, 0, 0);
    }
  }

  int node0 = nbase + w * 16 + lk * 4;
#pragma unroll
  for (int t = 0; t < 6; ++t) {
    int j = t * 16 + lrow;
    float bb1 = b1[j], bb2 = b2[j];
#pragma unroll
    for (int i = 0; i < 4; ++i) {
      int node = node0 + i;
      if (node < NN)
        out[(size_t)node * DD + j] = lrelu(acc1[t][i] + bb1) + lrelu(acc2[t][i] + bb2);
    }
  }
}

// ================= launch =================
extern "C" void kernel_launch(void* const* d_in, const int* in_sizes, int n_in,
                              void* d_out, int out_size, void* d_ws, size_t ws_size,
                              hipStream_t stream) {
  const float* ego   = (const float*)d_in[0];
  const float* avals = (const float*)d_in[1];
  const float* W1    = (const float*)d_in[2];
  const float* b1    = (const float*)d_in[3];
  const float* W2    = (const float*)d_in[4];
  const float* b2    = (const float*)d_in[5];
  const int* arows   = (const int*)d_in[6];
  const int* acols   = (const int*)d_in[7];
  float* out = (float*)d_out;

  size_t off = 0;
  auto bump = [&](size_t bytes) {
    size_t o = off;
    off += (bytes + 1023) & ~(size_t)1023;
    return o;
  };
  char* ws = (char*)d_ws;
  size_t o_rs    = bump((size_t)(NN + 1) * 4);
  size_t o_cv    = bump((size_t)NE * 4);
  size_t o_wb1   = bump((size_t)DD * DD * 2);
  size_t o_wb2   = bump((size_t)DD * DD * 2);
  size_t o_egob  = bump((size_t)NN * DD * 2);
  size_t o_bptr  = bump((size_t)(NBK + 1) * 4);  // bptr[NBK] + ovcur
  size_t o_ovbuf = bump((size_t)OVCAP * 8);
  size_t o_sbase = bump((size_t)(NBK + 1) * 4);
  size_t o_side  = bump((size_t)NN * DD * 4);    // also aliases bucket regions
  size_t need = off;
  // bucket regions (NBK*BCAP*8 = 18.8 MB) alias side (19.2 MB): buckets are
  // dead after binB, side is first written by agg afterwards.
  static_assert((size_t)NBK * BCAP * 8 <= (size_t)NN * DD * 4, "buckets fit in side");

  if (ws_size >= need) {
    int*  rs    = (int*)(ws + o_rs);
    unsigned* cv = (unsigned*)(ws + o_cv);
    unsigned short* Wb1  = (unsigned short*)(ws + o_wb1);
    unsigned short* Wb2  = (unsigned short*)(ws + o_wb2);
    unsigned short* egob = (unsigned short*)(ws + o_egob);
    int*  bptr  = (int*)(ws + o_bptr);
    int*  ovcur = bptr + NBK;
    int2* ovbuf = (int2*)(ws + o_ovbuf);
    int*  sbase = (int*)(ws + o_sbase);
    float* side = (float*)(ws + o_side);
    int2* buckets = (int2*)(ws + o_side);

    hipMemsetAsync(bptr, 0, (size_t)(NBK + 1) * 4, stream);
    prep_conv_kernel<<<NB_W + NB_E, 256, 0, stream>>>(W1, W2, Wb1, Wb2, ego, egob);
    binA_kernel<<<NA, 256, 0, stream>>>(arows, acols, avals, bptr, ovcur, ovbuf, buckets);
    scanb_kernel<<<1, 256, 0, stream>>>(bptr, sbase);
    binB_kernel<<<NBK, 256, 0, stream>>>(buckets, bptr, sbase, ovcur, ovbuf, cv, rs);
    agg_kernel<<<(NN + 3) / 4, 256, 0, stream>>>(egob, rs, cv, side);
    fuse4_kernel<<<(NN + FN - 1) / FN, 256, 0, stream>>>(
        ego, side, Wb1, Wb2, b1, b2, out);
  } else {
    size_t side_bytes = (size_t)NN * DD * sizeof(float);
    float* side = (ws_size >= side_bytes) ? (float*)d_ws : out;
    hipMemsetAsync(side, 0, side_bytes, stream);
    long long nthreads = (long long)NE * 32;
    int blocks = (int)((nthreads + 255) / 256);
    scatter_kernel<<<blocks, 256, 0, stream>>>(ego, avals, arows, acols, side);
    fuse_fb_kernel<<<1024, 192, 0, stream>>>(ego, side, W1, b1, W2, b2, out);
  }
}

// Round 10
// 102.093 us; speedup vs baseline: 4.5459x; 1.0711x over previous
//
#include <hip/hip_runtime.h>

#define NN 50000
#define NE 800000
#define DD 96
#define NEG 0.01f
#define FN 64        // nodes per fuse4 block
#define XST 104      // LDS row stride (bf16 units)
#define NBK 196      // buckets = row>>8 (256 rows each)
#define BCAP 4600    // bucket region capacity (mean 4096, sigma 64; overflow exact)
#define EPA 4096     // edges per binA block
#define NBA 196      // binA blocks: 196*4096 = 802816 >= NE
#define OVCAP 65536  // overflow list capacity (normally 0 used)
#define EGST 128     // padded egob row stride (bf16 units) -> 256B rows, shift addressing

typedef __attribute__((ext_vector_type(8))) short short8v;
typedef __attribute__((ext_vector_type(4))) short short4v;
typedef __attribute__((ext_vector_type(4))) float f32x4;

static __device__ __forceinline__ float lrelu(float x) {
  return (x >= 0.f) ? x : NEG * x;
}
static __device__ __forceinline__ unsigned short f2bf(float x) {
  unsigned u = __float_as_uint(x);
  u += 0x7fffu + ((u >> 16) & 1u);   // RNE
  return (unsigned short)(u >> 16);
}
static __device__ __forceinline__ float bf2f(unsigned short h) {
  return __uint_as_float(((unsigned)h) << 16);
}
static __device__ __forceinline__ float bflo(unsigned u) {  // low bf16 of dword
  return __uint_as_float(u << 16);
}
static __device__ __forceinline__ float bfhi(unsigned u) {  // high bf16 of dword
  return __uint_as_float(u & 0xFFFF0000u);
}

// ================= fallback (round-1) path =================
__global__ __launch_bounds__(256) void scatter_kernel(
    const float* __restrict__ ego, const float* __restrict__ avals,
    const int* __restrict__ arows, const int* __restrict__ acols,
    float* __restrict__ side)
{
  int t = blockIdx.x * 256 + threadIdx.x;
  int e = t >> 5;
  int lane = t & 31;
  if (e >= NE) return;
  int row = arows[e];
  int col = acols[e];
  float v = avals[e];
  if (lane < 24) {
    const float4* src = (const float4*)(ego + (size_t)col * DD);
    float4 x = src[lane];
    float* dst = side + (size_t)row * DD + lane * 4;
    unsafeAtomicAdd(dst + 0, v * x.x);
    unsafeAtomicAdd(dst + 1, v * x.y);
    unsafeAtomicAdd(dst + 2, v * x.z);
    unsafeAtomicAdd(dst + 3, v * x.w);
  }
}

__global__ __launch_bounds__(192) void fuse_fb_kernel(
    const float* __restrict__ ego, const float* __restrict__ side,
    const float* __restrict__ W1, const float* __restrict__ b1,
    const float* __restrict__ W2, const float* __restrict__ b2,
    float* __restrict__ out)
{
  __shared__ float W1t[DD * DD];
  __shared__ float W2t[DD * DD];
  __shared__ float b1s[DD], b2s[DD];
  __shared__ float xs[192], ys[192];
  int tid = threadIdx.x;
  for (int i = tid; i < DD * DD; i += 192) {
    int j = i / DD, k = i - j * DD;
    W1t[k * DD + j] = W1[i];
    W2t[k * DD + j] = W2[i];
  }
  if (tid < DD) { b1s[tid] = b1[tid]; b2s[tid] = b2[tid]; }
  __syncthreads();
  int nl = tid / DD, j = tid - nl * DD;
  for (int p = blockIdx.x; p < NN / 2; p += gridDim.x) {
    int base = p * 192;
    float e = ego[base + tid], s = side[base + tid];
    xs[tid] = e + s; ys[tid] = e * s;
    __syncthreads();
    float a1 = b1s[j], a2 = b2s[j];
    const float* xr = xs + nl * DD;
    const float* yr = ys + nl * DD;
#pragma unroll 16
    for (int k = 0; k < DD; ++k) {
      a1 += xr[k] * W1t[k * DD + j];
      a2 += yr[k] * W2t[k * DD + j];
    }
    float r = lrelu(a1) + lrelu(a2);
    __syncthreads();
    out[base + tid] = r;
  }
}

// ========== build: binA binning + W->bf16 + ego->bf16(padded) in ONE dispatch ==========
#define NB_W   ((DD * DD) / 256)       // 36
#define NE8    (NN * DD / 8)           // 600000 short8 units
#define NB_E8  ((NE8 + 255) / 256)     // 2344
__global__ __launch_bounds__(256) void build_kernel(
    const int* __restrict__ rows, const int* __restrict__ cols,
    const float* __restrict__ vals,
    int* __restrict__ bptr, int* __restrict__ ovcur,
    int2* __restrict__ ovbuf, int2* __restrict__ buckets,
    const float* __restrict__ W1, const float* __restrict__ W2,
    unsigned short* __restrict__ Wb1, unsigned short* __restrict__ Wb2,
    const float* __restrict__ ego, unsigned short* __restrict__ egob)
{
  __shared__ unsigned sw0[EPA];
  __shared__ unsigned sw1[EPA];
  __shared__ unsigned char sbid[EPA];
  __shared__ int bcnt[256], bofs[256], gbase[256], stmp[256];

  int blk = blockIdx.x;
  int tid = threadIdx.x;

  if (blk >= NBA) {
    int b = blk - NBA;
    if (b < NB_W) {
      int i = b * 256 + tid;  // [0, 9216)
      Wb1[i] = f2bf(W1[i]);
      Wb2[i] = f2bf(W2[i]);
    } else {
      int i = (b - NB_W) * 256 + tid;
      if (i < NE8) {
        int r = i / 12, u = i - r * 12;
        const float4* src = (const float4*)(ego + (size_t)r * DD + u * 8);
        float4 v0 = src[0], v1 = src[1];
        short8v o;
        o[0] = (short)f2bf(v0.x); o[1] = (short)f2bf(v0.y);
        o[2] = (short)f2bf(v0.z); o[3] = (short)f2bf(v0.w);
        o[4] = (short)f2bf(v1.x); o[5] = (short)f2bf(v1.y);
        o[6] = (short)f2bf(v1.z); o[7] = (short)f2bf(v1.w);
        *(short8v*)(egob + (size_t)r * EGST + u * 8) = o;
      }
    }
    return;
  }

  // ---- binA part ----
  int base = blk * EPA;
  int cnt_here = min(EPA, NE - base);

  bcnt[tid] = 0;
  __syncthreads();

  unsigned w0[16], w1[16];
  int bb[16], lp[16];
#pragma unroll
  for (int k = 0; k < 16; ++k) {
    int i = tid + k * 256;
    bb[k] = -1;
    if (i < cnt_here) {
      int e = base + i;
      int r = rows[e], c = cols[e];
      float v = vals[e];
      int b = r >> 8;
      bb[k] = b;
      w0[k] = (unsigned)c | ((unsigned)(r & 255) << 16) | ((unsigned)b << 24);
      w1[k] = (unsigned)f2bf(v);
      lp[k] = atomicAdd(&bcnt[b], 1);
    }
  }
  __syncthreads();

  int v = bcnt[tid];
  stmp[tid] = v;
  __syncthreads();
  for (int off = 1; off < 256; off <<= 1) {
    int add = (tid >= off) ? stmp[tid - off] : 0;
    __syncthreads();
    stmp[tid] += add;
    __syncthreads();
  }
  bofs[tid] = stmp[tid] - v;  // exclusive
  gbase[tid] = (tid < NBK && v > 0) ? atomicAdd(&bptr[tid], v) : 0;
  __syncthreads();

#pragma unroll
  for (int k = 0; k < 16; ++k) {
    if (bb[k] >= 0) {
      int s = bofs[bb[k]] + lp[k];
      sw0[s] = w0[k];
      sw1[s] = w1[k];
      sbid[s] = (unsigned char)bb[k];
    }
  }
  __syncthreads();

  for (int i = tid; i < cnt_here; i += 256) {
    int b = sbid[i];
    int off = i - bofs[b];
    int g = gbase[b] + off;
    int2 ent = make_int2((int)sw0[i], (int)sw1[i]);
    if (g < BCAP) {
      buckets[(size_t)b * BCAP + g] = ent;
    } else {
      int op = atomicAdd(ovcur, 1);
      if (op < OVCAP) ovbuf[op] = ent;
    }
  }
}

// ========== binB: inline bucket-scan + per-bucket counting sort ==========
__global__ __launch_bounds__(256) void binB_kernel(
    const int2* __restrict__ buckets, const int* __restrict__ bptr,
    const int* __restrict__ ovcur, const int2* __restrict__ ovbuf,
    unsigned* __restrict__ cv, int* __restrict__ row_start)
{
  __shared__ int rcnt[256], rofs[256], rcur[256], stmp[256], sexc[256];
  int b = blockIdx.x, tid = threadIdx.x;

  // inline exclusive scan of the 196 bucket totals (replaces scanb dispatch)
  int bv = (tid < NBK) ? bptr[tid] : 0;
  stmp[tid] = bv;
  __syncthreads();
  for (int off = 1; off < 256; off <<= 1) {
    int add = (tid >= off) ? stmp[tid - off] : 0;
    __syncthreads();
    stmp[tid] += add;
    __syncthreads();
  }
  sexc[tid] = stmp[tid] - bv;
  __syncthreads();
  int cvb = sexc[b];
  int total = bptr[b];
  int nreg = min(total, BCAP);
  int nov = min(*ovcur, OVCAP);
  const int2* reg = buckets + (size_t)b * BCAP;

  rcnt[tid] = 0;
  __syncthreads();

  for (int i = tid; i < nreg; i += 256) {
    unsigned w0 = (unsigned)reg[i].x;
    atomicAdd(&rcnt[(w0 >> 16) & 255], 1);
  }
  for (int i = tid; i < nov; i += 256) {
    unsigned w0 = (unsigned)ovbuf[i].x;
    if ((w0 >> 24) == (unsigned)b) atomicAdd(&rcnt[(w0 >> 16) & 255], 1);
  }
  __syncthreads();

  int v = rcnt[tid];
  stmp[tid] = v;
  __syncthreads();
  for (int off = 1; off < 256; off <<= 1) {
    int add = (tid >= off) ? stmp[tid - off] : 0;
    __syncthreads();
    stmp[tid] += add;
    __syncthreads();
  }
  rofs[tid] = stmp[tid] - v;
  rcur[tid] = rofs[tid];
  int grow = b * 256 + tid;
  if (grow <= NN) row_start[grow] = cvb + rofs[tid];
  __syncthreads();

  for (int i = tid; i < nreg; i += 256) {
    unsigned w0 = (unsigned)reg[i].x;
    unsigned w1 = (unsigned)reg[i].y;
    int rl = (w0 >> 16) & 255;
    int p = atomicAdd(&rcur[rl], 1);
    cv[cvb + p] = (w0 & 0xFFFFu) | (w1 << 16);
  }
  for (int i = tid; i < nov; i += 256) {
    unsigned w0 = (unsigned)ovbuf[i].x;
    unsigned w1 = (unsigned)ovbuf[i].y;
    if ((w0 >> 24) == (unsigned)b) {
      int rl = (w0 >> 16) & 255;
      int p = atomicAdd(&rcur[rl], 1);
      cv[cvb + p] = (w0 & 0xFFFFu) | (w1 << 16);
    }
  }
}

// ====== agg: wave/row, shift-addressed bf16 gathers, bf16 side output ======
__global__ __launch_bounds__(256) void agg_kernel(
    const unsigned short* __restrict__ egob, const int* __restrict__ row_start,
    const unsigned* __restrict__ cv, unsigned* __restrict__ sideb) {
  int wid = threadIdx.x >> 6, lane = threadIdx.x & 63;
  int row = blockIdx.x * 4 + wid;
  if (row >= NN) return;
  int s = row_start[row], e = row_start[row + 1];
  int half = lane >> 5, hl = lane & 31;
  int hl8 = hl * 8;                 // byte offset of this lane's 4 bf16
  const char* egb = (const char*)egob;
  float4 a[8];
#pragma unroll
  for (int d = 0; d < 8; ++d) a[d] = make_float4(0.f, 0.f, 0.f, 0.f);

  for (int base = s; base < e; base += 64) {
    int idx = base + lane;
    unsigned pk = 0;                // col=0, val=+0.0 -> contributes 0
    if (idx < e) pk = cv[idx];
    int n = min(64, e - base);
    for (int i = 0; i < n; i += 16) {
#pragma unroll
      for (int d = 0; d < 8; ++d) {
        unsigned p = __shfl(pk, i + 2 * d + half, 64);
        float v = bfhi(p);                          // val bf16 in high half
        unsigned boff = ((p & 0xFFFFu) << 8) + hl8; // row c at c*256 bytes
        if (hl < 24) {
          uint2 u = *(const uint2*)(egb + boff);
          a[d].x += v * bflo(u.x);
          a[d].y += v * bfhi(u.x);
          a[d].z += v * bflo(u.y);
          a[d].w += v * bfhi(u.y);
        }
      }
    }
  }
  float4 acc;
  acc.x = ((a[0].x + a[1].x) + (a[2].x + a[3].x)) + ((a[4].x + a[5].x) + (a[6].x + a[7].x));
  acc.y = ((a[0].y + a[1].y) + (a[2].y + a[3].y)) + ((a[4].y + a[5].y) + (a[6].y + a[7].y));
  acc.z = ((a[0].z + a[1].z) + (a[2].z + a[3].z)) + ((a[4].z + a[5].z) + (a[6].z + a[7].z));
  acc.w = ((a[0].w + a[1].w) + (a[2].w + a[3].w)) + ((a[4].w + a[5].w) + (a[6].w + a[7].w));
  acc.x += __shfl(acc.x, lane ^ 32, 64);
  acc.y += __shfl(acc.y, lane ^ 32, 64);
  acc.z += __shfl(acc.z, lane ^ 32, 64);
  acc.w += __shfl(acc.w, lane ^ 32, 64);
  if (half == 0 && hl < 24) {
    unsigned lo = (unsigned)f2bf(acc.x) | ((unsigned)f2bf(acc.y) << 16);
    unsigned hi = (unsigned)f2bf(acc.z) | ((unsigned)f2bf(acc.w) << 16);
    *(uint2*)(sideb + (size_t)row * 48 + hl * 2) = make_uint2(lo, hi);
  }
}

// ========== fuse4: bf16 MFMA, staged from egob(padded)+sideb ==========
__global__ __launch_bounds__(256) void fuse4_kernel(
    const unsigned short* __restrict__ egob, const unsigned* __restrict__ sideb,
    const unsigned short* __restrict__ Wb1, const unsigned short* __restrict__ Wb2,
    const float* __restrict__ b1, const float* __restrict__ b2,
    float* __restrict__ out)
{
  __shared__ unsigned short xs[FN * XST];
  __shared__ unsigned short ys[FN * XST];
  int tid = threadIdx.x;
  int nbase = blockIdx.x * FN;

  // stage x=e+s, y=e*s as bf16; FN*12 short8 units, 3 iters/thread
  for (int i = tid; i < FN * 12; i += 256) {
    int r = i / 12, u = i - r * 12;
    short8v ev = {0,0,0,0,0,0,0,0}, sv = ev;
    if (nbase + r < NN) {
      ev = *(const short8v*)(egob + (size_t)(nbase + r) * EGST + u * 8);
      sv = *(const short8v*)((const unsigned short*)sideb + (size_t)(nbase + r) * DD + u * 8);
    }
    short8v xv, yv;
#pragma unroll
    for (int q = 0; q < 8; ++q) {
      float ef = bf2f((unsigned short)ev[q]);
      float sf = bf2f((unsigned short)sv[q]);
      xv[q] = (short)f2bf(ef + sf);
      yv[q] = (short)f2bf(ef * sf);
    }
    *(short8v*)(xs + r * XST + u * 8) = xv;
    *(short8v*)(ys + r * XST + u * 8) = yv;
  }
  __syncthreads();

  int w = tid >> 6, l = tid & 63;
  int lrow = l & 15, lk = l >> 4;

  f32x4 acc1[6], acc2[6];
#pragma unroll
  for (int t = 0; t < 6; ++t) {
    acc1[t] = (f32x4){0.f, 0.f, 0.f, 0.f};
    acc2[t] = (f32x4){0.f, 0.f, 0.f, 0.f};
  }

  const unsigned short* xrow = xs + (w * 16 + lrow) * XST + lk * 8;
  const unsigned short* yrow = ys + (w * 16 + lrow) * XST + lk * 8;

#pragma unroll
  for (int kk = 0; kk < 3; ++kk) {
    short8v ax = *(const short8v*)(xrow + kk * 32);
    short8v ay = *(const short8v*)(yrow + kk * 32);
    int kb = kk * 32 + lk * 8;
#pragma unroll
    for (int t = 0; t < 6; ++t) {
      int j = t * 16 + lrow;
      short8v bw1 = *(const short8v*)(Wb1 + j * DD + kb);
      short8v bw2 = *(const short8v*)(Wb2 + j * DD + kb);
      acc1[t] = __builtin_amdgcn_mfma_f32_16x16x32_bf16(ax, bw1, acc1[t], 0, 0, 0);
      acc2[t] = __builtin_amdgcn_mfma_f32_16x16x32_bf16(ay, bw2, acc2[t], 0, 0, 0);
    }
  }

  int node0 = nbase + w * 16 + lk * 4;
#pragma unroll
  for (int t = 0; t < 6; ++t) {
    int j = t * 16 + lrow;
    float bb1 = b1[j], bb2 = b2[j];
#pragma unroll
    for (int i = 0; i < 4; ++i) {
      int node = node0 + i;
      if (node < NN)
        out[(size_t)node * DD + j] = lrelu(acc1[t][i] + bb1) + lrelu(acc2[t][i] + bb2);
    }
  }
}

// ================= launch =================
extern "C" void kernel_launch(void* const* d_in, const int* in_sizes, int n_in,
                              void* d_out, int out_size, void* d_ws, size_t ws_size,
                              hipStream_t stream) {
  const float* ego   = (const float*)d_in[0];
  const float* avals = (const float*)d_in[1];
  const float* W1    = (const float*)d_in[2];
  const float* b1    = (const float*)d_in[3];
  const float* W2    = (const float*)d_in[4];
  const float* b2    = (const float*)d_in[5];
  const int* arows   = (const int*)d_in[6];
  const int* acols   = (const int*)d_in[7];
  float* out = (float*)d_out;

  size_t off = 0;
  auto bump = [&](size_t bytes) {
    size_t o = off;
    off += (bytes + 1023) & ~(size_t)1023;
    return o;
  };
  char* ws = (char*)d_ws;
  size_t o_rs    = bump((size_t)(NN + 1) * 4);
  size_t o_cv    = bump((size_t)NE * 4);
  size_t o_wb1   = bump((size_t)DD * DD * 2);
  size_t o_wb2   = bump((size_t)DD * DD * 2);
  size_t o_egob  = bump((size_t)NN * EGST * 2);   // padded rows, 12.8 MB
  size_t o_bptr  = bump((size_t)(NBK + 1) * 4);   // bptr[NBK] + ovcur
  size_t o_ovbuf = bump((size_t)OVCAP * 8);
  size_t o_sideb = bump((size_t)NN * DD * 2);     // 9.6 MB; buckets alias here
  size_t need = off;
  // buckets (NBK*BCAP*8 = 7.2 MB) alias sideb (9.6 MB): buckets dead after
  // binB; sideb first written by agg afterwards.
  static_assert((size_t)NBK * BCAP * 8 <= (size_t)NN * DD * 2, "buckets fit in sideb");

  if (ws_size >= need) {
    int*  rs    = (int*)(ws + o_rs);
    unsigned* cv = (unsigned*)(ws + o_cv);
    unsigned short* Wb1  = (unsigned short*)(ws + o_wb1);
    unsigned short* Wb2  = (unsigned short*)(ws + o_wb2);
    unsigned short* egob = (unsigned short*)(ws + o_egob);
    int*  bptr  = (int*)(ws + o_bptr);
    int*  ovcur = bptr + NBK;
    int2* ovbuf = (int2*)(ws + o_ovbuf);
    unsigned* sideb = (unsigned*)(ws + o_sideb);
    int2* buckets = (int2*)(ws + o_sideb);

    hipMemsetAsync(bptr, 0, (size_t)(NBK + 1) * 4, stream);
    build_kernel<<<NBA + NB_W + NB_E8, 256, 0, stream>>>(
        arows, acols, avals, bptr, ovcur, ovbuf, buckets,
        W1, W2, Wb1, Wb2, ego, egob);
    binB_kernel<<<NBK, 256, 0, stream>>>(buckets, bptr, ovcur, ovbuf, cv, rs);
    agg_kernel<<<(NN + 3) / 4, 256, 0, stream>>>(egob, rs, cv, sideb);
    fuse4_kernel<<<(NN + FN - 1) / FN, 256, 0, stream>>>(
        egob, sideb, Wb1, Wb2, b1, b2, out);
  } else {
    size_t side_bytes = (size_t)NN * DD * sizeof(float);
    float* side = (ws_size >= side_bytes) ? (float*)d_ws : out;
    hipMemsetAsync(side, 0, side_bytes, stream);
    long long nthreads = (long long)NE * 32;
    int blocks = (int)((nthreads + 255) / 256);
    scatter_kernel<<<blocks, 256, 0, stream>>>(ego, avals, arows, acols, side);
    fuse_fb_kernel<<<1024, 192, 0, stream>>>(ego, side, W1, b1, W2, b2, out);
  }
}

// Round 11
// 99.477 us; speedup vs baseline: 4.6655x; 1.0263x over previous
//
#include <hip/hip_runtime.h>

#define NN 50000
#define NE 800000
#define DD 96
#define NEG 0.01f
#define FN 64        // nodes per fuse4 block
#define XST 104      // LDS row stride (bf16 units); 208B rows keep 16B align
#define NBK 196      // buckets = row>>8 (256 rows each)
#define BCAP 4600    // bucket region capacity (mean 4096, sigma 64; overflow exact)
#define EPA 4096     // edges per binA block
#define NBA 196      // binA blocks: 196*4096 = 802816 >= NE
#define OVCAP 65536  // overflow list capacity (normally 0 used)
#define QROW 128     // egoq row stride in BYTES: [f32 scale][96 int8][pad]

typedef __attribute__((ext_vector_type(8))) short short8v;
typedef __attribute__((ext_vector_type(4))) float f32x4;

static __device__ __forceinline__ float lrelu(float x) {
  return (x >= 0.f) ? x : NEG * x;
}
static __device__ __forceinline__ unsigned short f2bf(float x) {
  unsigned u = __float_as_uint(x);
  u += 0x7fffu + ((u >> 16) & 1u);   // RNE
  return (unsigned short)(u >> 16);
}
static __device__ __forceinline__ float bf2f(unsigned short h) {
  return __uint_as_float(((unsigned)h) << 16);
}
static __device__ __forceinline__ float bflo(unsigned u) {
  return __uint_as_float(u << 16);
}
static __device__ __forceinline__ float bfhi(unsigned u) {
  return __uint_as_float(u & 0xFFFF0000u);
}

// ================= fallback (round-1) path =================
__global__ __launch_bounds__(256) void scatter_kernel(
    const float* __restrict__ ego, const float* __restrict__ avals,
    const int* __restrict__ arows, const int* __restrict__ acols,
    float* __restrict__ side)
{
  int t = blockIdx.x * 256 + threadIdx.x;
  int e = t >> 5;
  int lane = t & 31;
  if (e >= NE) return;
  int row = arows[e];
  int col = acols[e];
  float v = avals[e];
  if (lane < 24) {
    const float4* src = (const float4*)(ego + (size_t)col * DD);
    float4 x = src[lane];
    float* dst = side + (size_t)row * DD + lane * 4;
    unsafeAtomicAdd(dst + 0, v * x.x);
    unsafeAtomicAdd(dst + 1, v * x.y);
    unsafeAtomicAdd(dst + 2, v * x.z);
    unsafeAtomicAdd(dst + 3, v * x.w);
  }
}

__global__ __launch_bounds__(192) void fuse_fb_kernel(
    const float* __restrict__ ego, const float* __restrict__ side,
    const float* __restrict__ W1, const float* __restrict__ b1,
    const float* __restrict__ W2, const float* __restrict__ b2,
    float* __restrict__ out)
{
  __shared__ float W1t[DD * DD];
  __shared__ float W2t[DD * DD];
  __shared__ float b1s[DD], b2s[DD];
  __shared__ float xs[192], ys[192];
  int tid = threadIdx.x;
  for (int i = tid; i < DD * DD; i += 192) {
    int j = i / DD, k = i - j * DD;
    W1t[k * DD + j] = W1[i];
    W2t[k * DD + j] = W2[i];
  }
  if (tid < DD) { b1s[tid] = b1[tid]; b2s[tid] = b2[tid]; }
  __syncthreads();
  int nl = tid / DD, j = tid - nl * DD;
  for (int p = blockIdx.x; p < NN / 2; p += gridDim.x) {
    int base = p * 192;
    float e = ego[base + tid], s = side[base + tid];
    xs[tid] = e + s; ys[tid] = e * s;
    __syncthreads();
    float a1 = b1s[j], a2 = b2s[j];
    const float* xr = xs + nl * DD;
    const float* yr = ys + nl * DD;
#pragma unroll 16
    for (int k = 0; k < DD; ++k) {
      a1 += xr[k] * W1t[k * DD + j];
      a2 += yr[k] * W2t[k * DD + j];
    }
    float r = lrelu(a1) + lrelu(a2);
    __syncthreads();
    out[base + tid] = r;
  }
}

// ========== build: binA binning + W->bf16 + ego->int8(row-scale) ==========
#define NB_W   ((DD * DD) / 256)       // 36
#define NB_Q   ((NN + 63) / 64)        // 782 quant blocks (64 rows each)
__global__ __launch_bounds__(256) void build_kernel(
    const int* __restrict__ rows, const int* __restrict__ cols,
    const float* __restrict__ vals,
    int* __restrict__ bptr, int* __restrict__ ovcur,
    int2* __restrict__ ovbuf, int2* __restrict__ buckets,
    const float* __restrict__ W1, const float* __restrict__ W2,
    unsigned short* __restrict__ Wb1, unsigned short* __restrict__ Wb2,
    const float* __restrict__ ego, unsigned char* __restrict__ egoq)
{
  __shared__ unsigned sw0[EPA];
  __shared__ unsigned sw1[EPA];
  __shared__ unsigned char sbid[EPA];
  __shared__ int bcnt[256], bofs[256], gbase[256], stmp[256];

  int blk = blockIdx.x;
  int tid = threadIdx.x;

  if (blk >= NBA) {
    int b = blk - NBA;
    if (b < NB_W) {
      int i = b * 256 + tid;  // [0, 9216)
      Wb1[i] = f2bf(W1[i]);
      Wb2[i] = f2bf(W2[i]);
    } else {
      // int8 quantization: 64 rows/block, 4 threads/row (24 values each)
      int r_loc = tid >> 2, q = tid & 3;
      int row = (b - NB_W) * 64 + r_loc;
      if (row < NN) {
        float4 f[6];
        const float4* src = (const float4*)(ego + (size_t)row * DD + q * 24);
#pragma unroll
        for (int t = 0; t < 6; ++t) f[t] = src[t];
        float m = 0.f;
#pragma unroll
        for (int t = 0; t < 6; ++t) {
          m = fmaxf(m, fmaxf(fmaxf(fabsf(f[t].x), fabsf(f[t].y)),
                             fmaxf(fabsf(f[t].z), fabsf(f[t].w))));
        }
        m = fmaxf(m, __shfl_xor(m, 1, 64));
        m = fmaxf(m, __shfl_xor(m, 2, 64));
        m = fmaxf(m, 1e-20f);
        float inv = 127.0f / m;
        unsigned* dst = (unsigned*)(egoq + (size_t)row * QROW + 4) + q * 6;
#pragma unroll
        for (int t = 0; t < 6; ++t) {
          int q0 = __float2int_rn(f[t].x * inv);
          int q1 = __float2int_rn(f[t].y * inv);
          int q2 = __float2int_rn(f[t].z * inv);
          int q3 = __float2int_rn(f[t].w * inv);
          dst[t] = (unsigned)(q0 & 255) | ((unsigned)(q1 & 255) << 8) |
                   ((unsigned)(q2 & 255) << 16) | ((unsigned)(q3 & 255) << 24);
        }
        if (q == 0) *(float*)(egoq + (size_t)row * QROW) = m * (1.0f / 127.0f);
      }
    }
    return;
  }

  // ---- binA part ----
  int base = blk * EPA;
  int cnt_here = min(EPA, NE - base);

  bcnt[tid] = 0;
  __syncthreads();

  unsigned w0[16], w1[16];
  int bb[16], lp[16];
#pragma unroll
  for (int k = 0; k < 16; ++k) {
    int i = tid + k * 256;
    bb[k] = -1;
    if (i < cnt_here) {
      int e = base + i;
      int r = rows[e], c = cols[e];
      float v = vals[e];
      int b = r >> 8;
      bb[k] = b;
      w0[k] = (unsigned)c | ((unsigned)(r & 255) << 16) | ((unsigned)b << 24);
      w1[k] = (unsigned)f2bf(v);
      lp[k] = atomicAdd(&bcnt[b], 1);
    }
  }
  __syncthreads();

  int v = bcnt[tid];
  stmp[tid] = v;
  __syncthreads();
  for (int off = 1; off < 256; off <<= 1) {
    int add = (tid >= off) ? stmp[tid - off] : 0;
    __syncthreads();
    stmp[tid] += add;
    __syncthreads();
  }
  bofs[tid] = stmp[tid] - v;  // exclusive
  gbase[tid] = (tid < NBK && v > 0) ? atomicAdd(&bptr[tid], v) : 0;
  __syncthreads();

#pragma unroll
  for (int k = 0; k < 16; ++k) {
    if (bb[k] >= 0) {
      int s = bofs[bb[k]] + lp[k];
      sw0[s] = w0[k];
      sw1[s] = w1[k];
      sbid[s] = (unsigned char)bb[k];
    }
  }
  __syncthreads();

  for (int i = tid; i < cnt_here; i += 256) {
    int b = sbid[i];
    int off = i - bofs[b];
    int g = gbase[b] + off;
    int2 ent = make_int2((int)sw0[i], (int)sw1[i]);
    if (g < BCAP) {
      buckets[(size_t)b * BCAP + g] = ent;
    } else {
      int op = atomicAdd(ovcur, 1);
      if (op < OVCAP) ovbuf[op] = ent;
    }
  }
}

// ========== binB: inline bucket-scan + per-bucket counting sort ==========
__global__ __launch_bounds__(256) void binB_kernel(
    const int2* __restrict__ buckets, const int* __restrict__ bptr,
    const int* __restrict__ ovcur, const int2* __restrict__ ovbuf,
    unsigned* __restrict__ cv, int* __restrict__ row_start)
{
  __shared__ int rcnt[256], rofs[256], rcur[256], stmp[256], sexc[256];
  int b = blockIdx.x, tid = threadIdx.x;

  int bv = (tid < NBK) ? bptr[tid] : 0;
  stmp[tid] = bv;
  __syncthreads();
  for (int off = 1; off < 256; off <<= 1) {
    int add = (tid >= off) ? stmp[tid - off] : 0;
    __syncthreads();
    stmp[tid] += add;
    __syncthreads();
  }
  sexc[tid] = stmp[tid] - bv;
  __syncthreads();
  int cvb = sexc[b];
  int total = bptr[b];
  int nreg = min(total, BCAP);
  int nov = min(*ovcur, OVCAP);
  const int2* reg = buckets + (size_t)b * BCAP;

  rcnt[tid] = 0;
  __syncthreads();

  for (int i = tid; i < nreg; i += 256) {
    unsigned w0 = (unsigned)reg[i].x;
    atomicAdd(&rcnt[(w0 >> 16) & 255], 1);
  }
  for (int i = tid; i < nov; i += 256) {
    unsigned w0 = (unsigned)ovbuf[i].x;
    if ((w0 >> 24) == (unsigned)b) atomicAdd(&rcnt[(w0 >> 16) & 255], 1);
  }
  __syncthreads();

  int v = rcnt[tid];
  stmp[tid] = v;
  __syncthreads();
  for (int off = 1; off < 256; off <<= 1) {
    int add = (tid >= off) ? stmp[tid - off] : 0;
    __syncthreads();
    stmp[tid] += add;
    __syncthreads();
  }
  rofs[tid] = stmp[tid] - v;
  rcur[tid] = rofs[tid];
  int grow = b * 256 + tid;
  if (grow <= NN) row_start[grow] = cvb + rofs[tid];
  __syncthreads();

  for (int i = tid; i < nreg; i += 256) {
    unsigned w0 = (unsigned)reg[i].x;
    unsigned w1 = (unsigned)reg[i].y;
    int rl = (w0 >> 16) & 255;
    int p = atomicAdd(&rcur[rl], 1);
    cv[cvb + p] = (w0 & 0xFFFFu) | (w1 << 16);
  }
  for (int i = tid; i < nov; i += 256) {
    unsigned w0 = (unsigned)ovbuf[i].x;
    unsigned w1 = (unsigned)ovbuf[i].y;
    if ((w0 >> 24) == (unsigned)b) {
      int rl = (w0 >> 16) & 255;
      int p = atomicAdd(&rcur[rl], 1);
      cv[cvb + p] = (w0 & 0xFFFFu) | (w1 << 16);
    }
  }
}

// ====== agg: wave/row, int8 row-scale gathers, bf16 side output ======
__global__ __launch_bounds__(256) void agg_kernel(
    const unsigned char* __restrict__ egoq, const int* __restrict__ row_start,
    const unsigned* __restrict__ cv, unsigned* __restrict__ sideb) {
  int wid = threadIdx.x >> 6, lane = threadIdx.x & 63;
  int row = blockIdx.x * 4 + wid;
  if (row >= NN) return;
  int s = row_start[row], e = row_start[row + 1];
  int half = lane >> 5, hl = lane & 31;
  float4 a[8];
#pragma unroll
  for (int d = 0; d < 8; ++d) a[d] = make_float4(0.f, 0.f, 0.f, 0.f);

  for (int base = s; base < e; base += 64) {
    int idx = base + lane;
    unsigned pk = 0;                // col=0, val=+0.0 -> contributes 0
    if (idx < e) pk = cv[idx];
    int n = min(64, e - base);
    for (int i = 0; i < n; i += 16) {
#pragma unroll
      for (int d = 0; d < 8; ++d) {
        unsigned p = __shfl(pk, i + 2 * d + half, 64);
        float v = bfhi(p);                          // val bf16 in high half
        const char* rowp = (const char*)egoq + ((size_t)(p & 0xFFFFu) << 7);
        if (hl < 24) {
          float sc = *(const float*)rowp;           // same addr for 24 lanes
          unsigned u = *(const unsigned*)(rowp + 4 + hl * 4);
          float vs = v * sc;
          a[d].x += vs * (float)((int)(signed char)(u & 0xFF));
          a[d].y += vs * (float)((int)(signed char)((u >> 8) & 0xFF));
          a[d].z += vs * (float)((int)(signed char)((u >> 16) & 0xFF));
          a[d].w += vs * (float)(((int)u) >> 24);
        }
      }
    }
  }
  float4 acc;
  acc.x = ((a[0].x + a[1].x) + (a[2].x + a[3].x)) + ((a[4].x + a[5].x) + (a[6].x + a[7].x));
  acc.y = ((a[0].y + a[1].y) + (a[2].y + a[3].y)) + ((a[4].y + a[5].y) + (a[6].y + a[7].y));
  acc.z = ((a[0].z + a[1].z) + (a[2].z + a[3].z)) + ((a[4].z + a[5].z) + (a[6].z + a[7].z));
  acc.w = ((a[0].w + a[1].w) + (a[2].w + a[3].w)) + ((a[4].w + a[5].w) + (a[6].w + a[7].w));
  acc.x += __shfl(acc.x, lane ^ 32, 64);
  acc.y += __shfl(acc.y, lane ^ 32, 64);
  acc.z += __shfl(acc.z, lane ^ 32, 64);
  acc.w += __shfl(acc.w, lane ^ 32, 64);
  if (half == 0 && hl < 24) {
    unsigned lo = (unsigned)f2bf(acc.x) | ((unsigned)f2bf(acc.y) << 16);
    unsigned hi = (unsigned)f2bf(acc.z) | ((unsigned)f2bf(acc.w) << 16);
    *(uint2*)(sideb + (size_t)row * 48 + hl * 2) = make_uint2(lo, hi);
  }
}

// ========== fuse4: bf16 MFMA, staged from egoq(int8)+sideb(bf16) ==========
__global__ __launch_bounds__(256) void fuse4_kernel(
    const unsigned char* __restrict__ egoq, const unsigned* __restrict__ sideb,
    const unsigned short* __restrict__ Wb1, const unsigned short* __restrict__ Wb2,
    const float* __restrict__ b1, const float* __restrict__ b2,
    float* __restrict__ out)
{
  __shared__ unsigned short xs[FN * XST];
  __shared__ unsigned short ys[FN * XST];
  int tid = threadIdx.x;
  int nbase = blockIdx.x * FN;

  // stage x=e+s, y=e*s as bf16; FN*24 dword units, 6 iters/thread
  for (int i = tid; i < FN * 24; i += 256) {
    int r = i / 24, u = i - r * 24;
    float e0 = 0.f, e1 = 0.f, e2 = 0.f, e3 = 0.f;
    float s0 = 0.f, s1 = 0.f, s2 = 0.f, s3 = 0.f;
    if (nbase + r < NN) {
      const char* rowp = (const char*)egoq + ((size_t)(nbase + r) << 7);
      float sc = *(const float*)rowp;
      unsigned uq = *(const unsigned*)(rowp + 4 + u * 4);
      e0 = sc * (float)((int)(signed char)(uq & 0xFF));
      e1 = sc * (float)((int)(signed char)((uq >> 8) & 0xFF));
      e2 = sc * (float)((int)(signed char)((uq >> 16) & 0xFF));
      e3 = sc * (float)(((int)uq) >> 24);
      uint2 sv = *(const uint2*)(sideb + (size_t)(nbase + r) * 48 + u * 2);
      s0 = bflo(sv.x); s1 = bfhi(sv.x);
      s2 = bflo(sv.y); s3 = bfhi(sv.y);
    }
    unsigned xlo = (unsigned)f2bf(e0 + s0) | ((unsigned)f2bf(e1 + s1) << 16);
    unsigned xhi = (unsigned)f2bf(e2 + s2) | ((unsigned)f2bf(e3 + s3) << 16);
    unsigned ylo = (unsigned)f2bf(e0 * s0) | ((unsigned)f2bf(e1 * s1) << 16);
    unsigned yhi = (unsigned)f2bf(e2 * s2) | ((unsigned)f2bf(e3 * s3) << 16);
    *(uint2*)(xs + r * XST + u * 4) = make_uint2(xlo, xhi);
    *(uint2*)(ys + r * XST + u * 4) = make_uint2(ylo, yhi);
  }
  __syncthreads();

  int w = tid >> 6, l = tid & 63;
  int lrow = l & 15, lk = l >> 4;

  f32x4 acc1[6], acc2[6];
#pragma unroll
  for (int t = 0; t < 6; ++t) {
    acc1[t] = (f32x4){0.f, 0.f, 0.f, 0.f};
    acc2[t] = (f32x4){0.f, 0.f, 0.f, 0.f};
  }

  const unsigned short* xrow = xs + (w * 16 + lrow) * XST + lk * 8;
  const unsigned short* yrow = ys + (w * 16 + lrow) * XST + lk * 8;

#pragma unroll
  for (int kk = 0; kk < 3; ++kk) {
    short8v ax = *(const short8v*)(xrow + kk * 32);
    short8v ay = *(const short8v*)(yrow + kk * 32);
    int kb = kk * 32 + lk * 8;
#pragma unroll
    for (int t = 0; t < 6; ++t) {
      int j = t * 16 + lrow;
      short8v bw1 = *(const short8v*)(Wb1 + j * DD + kb);
      short8v bw2 = *(const short8v*)(Wb2 + j * DD + kb);
      acc1[t] = __builtin_amdgcn_mfma_f32_16x16x32_bf16(ax, bw1, acc1[t], 0, 0, 0);
      acc2[t] = __builtin_amdgcn_mfma_f32_16x16x32_bf16(ay, bw2, acc2[t], 0, 0, 0);
    }
  }

  int node0 = nbase + w * 16 + lk * 4;
#pragma unroll
  for (int t = 0; t < 6; ++t) {
    int j = t * 16 + lrow;
    float bb1 = b1[j], bb2 = b2[j];
#pragma unroll
    for (int i = 0; i < 4; ++i) {
      int node = node0 + i;
      if (node < NN)
        out[(size_t)node * DD + j] = lrelu(acc1[t][i] + bb1) + lrelu(acc2[t][i] + bb2);
    }
  }
}

// ================= launch =================
extern "C" void kernel_launch(void* const* d_in, const int* in_sizes, int n_in,
                              void* d_out, int out_size, void* d_ws, size_t ws_size,
                              hipStream_t stream) {
  const float* ego   = (const float*)d_in[0];
  const float* avals = (const float*)d_in[1];
  const float* W1    = (const float*)d_in[2];
  const float* b1    = (const float*)d_in[3];
  const float* W2    = (const float*)d_in[4];
  const float* b2    = (const float*)d_in[5];
  const int* arows   = (const int*)d_in[6];
  const int* acols   = (const int*)d_in[7];
  float* out = (float*)d_out;

  size_t off = 0;
  auto bump = [&](size_t bytes) {
    size_t o = off;
    off += (bytes + 1023) & ~(size_t)1023;
    return o;
  };
  char* ws = (char*)d_ws;
  size_t o_rs    = bump((size_t)(NN + 1) * 4);
  size_t o_cv    = bump((size_t)NE * 4);
  size_t o_wb1   = bump((size_t)DD * DD * 2);
  size_t o_wb2   = bump((size_t)DD * DD * 2);
  size_t o_egoq  = bump((size_t)NN * QROW);       // 6.4 MB int8 rows w/ scale
  size_t o_bptr  = bump((size_t)(NBK + 1) * 4);   // bptr[NBK] + ovcur
  size_t o_ovbuf = bump((size_t)OVCAP * 8);
  size_t o_sideb = bump((size_t)NN * DD * 2);     // 9.6 MB; buckets alias here
  size_t need = off;
  static_assert((size_t)NBK * BCAP * 8 <= (size_t)NN * DD * 2, "buckets fit in sideb");

  if (ws_size >= need) {
    int*  rs    = (int*)(ws + o_rs);
    unsigned* cv = (unsigned*)(ws + o_cv);
    unsigned short* Wb1  = (unsigned short*)(ws + o_wb1);
    unsigned short* Wb2  = (unsigned short*)(ws + o_wb2);
    unsigned char* egoq  = (unsigned char*)(ws + o_egoq);
    int*  bptr  = (int*)(ws + o_bptr);
    int*  ovcur = bptr + NBK;
    int2* ovbuf = (int2*)(ws + o_ovbuf);
    unsigned* sideb = (unsigned*)(ws + o_sideb);
    int2* buckets = (int2*)(ws + o_sideb);

    hipMemsetAsync(bptr, 0, (size_t)(NBK + 1) * 4, stream);
    build_kernel<<<NBA + NB_W + NB_Q, 256, 0, stream>>>(
        arows, acols, avals, bptr, ovcur, ovbuf, buckets,
        W1, W2, Wb1, Wb2, ego, egoq);
    binB_kernel<<<NBK, 256, 0, stream>>>(buckets, bptr, ovcur, ovbuf, cv, rs);
    agg_kernel<<<(NN + 3) / 4, 256, 0, stream>>>(egoq, rs, cv, sideb);
    fuse4_kernel<<<(NN + FN - 1) / FN, 256, 0, stream>>>(
        egoq, sideb, Wb1, Wb2, b1, b2, out);
  } else {
    size_t side_bytes = (size_t)NN * DD * sizeof(float);
    float* side = (ws_size >= side_bytes) ? (float*)d_ws : out;
    hipMemsetAsync(side, 0, side_bytes, stream);
    long long nthreads = (long long)NE * 32;
    int blocks = (int)((nthreads + 255) / 256);
    scatter_kernel<<<blocks, 256, 0, stream>>>(ego, avals, arows, acols, side);
    fuse_fb_kernel<<<1024, 192, 0, stream>>>(ego, side, W1, b1, W2, b2, out);
  }
}

// Round 12
// 83.913 us; speedup vs baseline: 5.5308x; 1.1855x over previous
//
#include <hip/hip_runtime.h>

#define NN 50000
#define NE 800000
#define DD 96
#define NEG 0.01f
#define FN 64        // nodes per fuse4 block
#define XST 104      // LDS row stride (bf16 units)
#define NBK 196      // buckets = row>>8 (256 rows each)
#define BCAP 4600    // bucket region capacity (mean 4096, sigma 64; overflow exact)
#define EPA 4096     // edges per binA block
#define NBA 196      // binA blocks
#define OVCAP 65536  // overflow list capacity (normally 0 used)
#define QROW 128     // egoq row stride BYTES: [96 int8][f32 scale][pad]

typedef __attribute__((ext_vector_type(8))) short short8v;
typedef __attribute__((ext_vector_type(4))) float f32x4;

static __device__ __forceinline__ float lrelu(float x) {
  return (x >= 0.f) ? x : NEG * x;
}
static __device__ __forceinline__ unsigned short f2bf(float x) {
  unsigned u = __float_as_uint(x);
  u += 0x7fffu + ((u >> 16) & 1u);   // RNE
  return (unsigned short)(u >> 16);
}
static __device__ __forceinline__ float bf2f(unsigned short h) {
  return __uint_as_float(((unsigned)h) << 16);
}
static __device__ __forceinline__ float bflo(unsigned u) {
  return __uint_as_float(u << 16);
}
static __device__ __forceinline__ float bfhi(unsigned u) {
  return __uint_as_float(u & 0xFFFF0000u);
}
static __device__ __forceinline__ float sb(unsigned u, int k) {  // signed byte k -> f32
  return (float)((int)(signed char)((u >> (8 * k)) & 0xFF));
}

// ================= fallback (round-1) path =================
__global__ __launch_bounds__(256) void scatter_kernel(
    const float* __restrict__ ego, const float* __restrict__ avals,
    const int* __restrict__ arows, const int* __restrict__ acols,
    float* __restrict__ side)
{
  int t = blockIdx.x * 256 + threadIdx.x;
  int e = t >> 5;
  int lane = t & 31;
  if (e >= NE) return;
  int row = arows[e];
  int col = acols[e];
  float v = avals[e];
  if (lane < 24) {
    const float4* src = (const float4*)(ego + (size_t)col * DD);
    float4 x = src[lane];
    float* dst = side + (size_t)row * DD + lane * 4;
    unsafeAtomicAdd(dst + 0, v * x.x);
    unsafeAtomicAdd(dst + 1, v * x.y);
    unsafeAtomicAdd(dst + 2, v * x.z);
    unsafeAtomicAdd(dst + 3, v * x.w);
  }
}

__global__ __launch_bounds__(192) void fuse_fb_kernel(
    const float* __restrict__ ego, const float* __restrict__ side,
    const float* __restrict__ W1, const float* __restrict__ b1,
    const float* __restrict__ W2, const float* __restrict__ b2,
    float* __restrict__ out)
{
  __shared__ float W1t[DD * DD];
  __shared__ float W2t[DD * DD];
  __shared__ float b1s[DD], b2s[DD];
  __shared__ float xs[192], ys[192];
  int tid = threadIdx.x;
  for (int i = tid; i < DD * DD; i += 192) {
    int j = i / DD, k = i - j * DD;
    W1t[k * DD + j] = W1[i];
    W2t[k * DD + j] = W2[i];
  }
  if (tid < DD) { b1s[tid] = b1[tid]; b2s[tid] = b2[tid]; }
  __syncthreads();
  int nl = tid / DD, j = tid - nl * DD;
  for (int p = blockIdx.x; p < NN / 2; p += gridDim.x) {
    int base = p * 192;
    float e = ego[base + tid], s = side[base + tid];
    xs[tid] = e + s; ys[tid] = e * s;
    __syncthreads();
    float a1 = b1s[j], a2 = b2s[j];
    const float* xr = xs + nl * DD;
    const float* yr = ys + nl * DD;
#pragma unroll 16
    for (int k = 0; k < DD; ++k) {
      a1 += xr[k] * W1t[k * DD + j];
      a2 += yr[k] * W2t[k * DD + j];
    }
    float r = lrelu(a1) + lrelu(a2);
    __syncthreads();
    out[base + tid] = r;
  }
}

// ========== build: binA binning + W->bf16 + ego->int8(row-scale) ==========
#define NB_W   ((DD * DD) / 256)       // 36
#define NB_Q   ((NN + 63) / 64)        // 782 quant blocks (64 rows each)
__global__ __launch_bounds__(256) void build_kernel(
    const int* __restrict__ rows, const int* __restrict__ cols,
    const float* __restrict__ vals,
    int* __restrict__ bptr, int* __restrict__ ovcur,
    int2* __restrict__ ovbuf, int2* __restrict__ buckets,
    const float* __restrict__ W1, const float* __restrict__ W2,
    unsigned short* __restrict__ Wb1, unsigned short* __restrict__ Wb2,
    const float* __restrict__ ego, unsigned char* __restrict__ egoq)
{
  __shared__ unsigned sw0[EPA];
  __shared__ unsigned sw1[EPA];
  __shared__ unsigned char sbid[EPA];
  __shared__ int bcnt[256], bofs[256], gbase[256], stmp[256];

  int blk = blockIdx.x;
  int tid = threadIdx.x;

  if (blk >= NBA) {
    int b = blk - NBA;
    if (b < NB_W) {
      int i = b * 256 + tid;  // [0, 9216)
      Wb1[i] = f2bf(W1[i]);
      Wb2[i] = f2bf(W2[i]);
    } else {
      // int8 quantization: 64 rows/block, 4 threads/row (24 values each)
      int r_loc = tid >> 2, q = tid & 3;
      int row = (b - NB_W) * 64 + r_loc;
      if (row < NN) {
        float4 f[6];
        const float4* src = (const float4*)(ego + (size_t)row * DD + q * 24);
#pragma unroll
        for (int t = 0; t < 6; ++t) f[t] = src[t];
        float m = 0.f;
#pragma unroll
        for (int t = 0; t < 6; ++t) {
          m = fmaxf(m, fmaxf(fmaxf(fabsf(f[t].x), fabsf(f[t].y)),
                             fmaxf(fabsf(f[t].z), fabsf(f[t].w))));
        }
        m = fmaxf(m, __shfl_xor(m, 1, 64));
        m = fmaxf(m, __shfl_xor(m, 2, 64));
        m = fmaxf(m, 1e-20f);
        float inv = 127.0f / m;
        // layout: [96 int8][f32 scale]  -> data 8B-aligned at offset 0
        unsigned* dst = (unsigned*)(egoq + (size_t)row * QROW) + q * 6;
#pragma unroll
        for (int t = 0; t < 6; ++t) {
          int q0 = __float2int_rn(f[t].x * inv);
          int q1 = __float2int_rn(f[t].y * inv);
          int q2 = __float2int_rn(f[t].z * inv);
          int q3 = __float2int_rn(f[t].w * inv);
          dst[t] = (unsigned)(q0 & 255) | ((unsigned)(q1 & 255) << 8) |
                   ((unsigned)(q2 & 255) << 16) | ((unsigned)(q3 & 255) << 24);
        }
        if (q == 0) *(float*)(egoq + (size_t)row * QROW + DD) = m * (1.0f / 127.0f);
      }
    }
    return;
  }

  // ---- binA part ----
  int base = blk * EPA;
  int cnt_here = min(EPA, NE - base);

  bcnt[tid] = 0;
  __syncthreads();

  unsigned w0[16], w1[16];
  int bb[16], lp[16];
#pragma unroll
  for (int k = 0; k < 16; ++k) {
    int i = tid + k * 256;
    bb[k] = -1;
    if (i < cnt_here) {
      int e = base + i;
      int r = rows[e], c = cols[e];
      float v = vals[e];
      int b = r >> 8;
      bb[k] = b;
      w0[k] = (unsigned)c | ((unsigned)(r & 255) << 16) | ((unsigned)b << 24);
      w1[k] = (unsigned)f2bf(v);
      lp[k] = atomicAdd(&bcnt[b], 1);
    }
  }
  __syncthreads();

  int v = bcnt[tid];
  stmp[tid] = v;
  __syncthreads();
  for (int off = 1; off < 256; off <<= 1) {
    int add = (tid >= off) ? stmp[tid - off] : 0;
    __syncthreads();
    stmp[tid] += add;
    __syncthreads();
  }
  bofs[tid] = stmp[tid] - v;  // exclusive
  gbase[tid] = (tid < NBK && v > 0) ? atomicAdd(&bptr[tid], v) : 0;
  __syncthreads();

#pragma unroll
  for (int k = 0; k < 16; ++k) {
    if (bb[k] >= 0) {
      int s = bofs[bb[k]] + lp[k];
      sw0[s] = w0[k];
      sw1[s] = w1[k];
      sbid[s] = (unsigned char)bb[k];
    }
  }
  __syncthreads();

  for (int i = tid; i < cnt_here; i += 256) {
    int b = sbid[i];
    int off = i - bofs[b];
    int g = gbase[b] + off;
    int2 ent = make_int2((int)sw0[i], (int)sw1[i]);
    if (g < BCAP) {
      buckets[(size_t)b * BCAP + g] = ent;
    } else {
      int op = atomicAdd(ovcur, 1);
      if (op < OVCAP) ovbuf[op] = ent;
    }
  }
}

// ========== binB: LDS-staged bucket + counting sort -> cv + row_start ==========
__global__ __launch_bounds__(256) void binB_kernel(
    const int2* __restrict__ buckets, const int* __restrict__ bptr,
    const int* __restrict__ ovcur, const int2* __restrict__ ovbuf,
    unsigned* __restrict__ cv, int* __restrict__ row_start)
{
  __shared__ int2 sent[BCAP];
  __shared__ int rcnt[256], rofs[256], rcur[256], stmp[256], sexc[256];
  int b = blockIdx.x, tid = threadIdx.x;

  // inline exclusive scan of the 196 bucket totals
  int bv = (tid < NBK) ? bptr[tid] : 0;
  stmp[tid] = bv;
  __syncthreads();
  for (int off = 1; off < 256; off <<= 1) {
    int add = (tid >= off) ? stmp[tid - off] : 0;
    __syncthreads();
    stmp[tid] += add;
    __syncthreads();
  }
  sexc[tid] = stmp[tid] - bv;
  __syncthreads();
  int cvb = sexc[b];
  int total = bptr[b];
  int nreg = min(total, BCAP);
  int nov = min(*ovcur, OVCAP);
  const int2* reg = buckets + (size_t)b * BCAP;

  rcnt[tid] = 0;
  // stage this bucket's entries into LDS (single global read)
  for (int i = tid; i < nreg; i += 256) sent[i] = reg[i];
  __syncthreads();

  for (int i = tid; i < nreg; i += 256) {
    unsigned w0 = (unsigned)sent[i].x;
    atomicAdd(&rcnt[(w0 >> 16) & 255], 1);
  }
  for (int i = tid; i < nov; i += 256) {
    unsigned w0 = (unsigned)ovbuf[i].x;
    if ((w0 >> 24) == (unsigned)b) atomicAdd(&rcnt[(w0 >> 16) & 255], 1);
  }
  __syncthreads();

  int v = rcnt[tid];
  stmp[tid] = v;
  __syncthreads();
  for (int off = 1; off < 256; off <<= 1) {
    int add = (tid >= off) ? stmp[tid - off] : 0;
    __syncthreads();
    stmp[tid] += add;
    __syncthreads();
  }
  rofs[tid] = stmp[tid] - v;
  rcur[tid] = rofs[tid];
  int grow = b * 256 + tid;
  if (grow <= NN) row_start[grow] = cvb + rofs[tid];
  __syncthreads();

  for (int i = tid; i < nreg; i += 256) {
    unsigned w0 = (unsigned)sent[i].x;
    unsigned w1 = (unsigned)sent[i].y;
    int rl = (w0 >> 16) & 255;
    int p = atomicAdd(&rcur[rl], 1);
    cv[cvb + p] = (w0 & 0xFFFFu) | (w1 << 16);
  }
  for (int i = tid; i < nov; i += 256) {
    unsigned w0 = (unsigned)ovbuf[i].x;
    unsigned w1 = (unsigned)ovbuf[i].y;
    if ((w0 >> 24) == (unsigned)b) {
      int rl = (w0 >> 16) & 255;
      int p = atomicAdd(&rcur[rl], 1);
      cv[cvb + p] = (w0 & 0xFFFFu) | (w1 << 16);
    }
  }
}

// ====== agg: wave/row, quarter-wave gathers, 3-phase pipeline ======
// Quarter q handles edge slot i+4d+q; lane ql<12 loads uint2 (8 int8).
// Phases per 16-edge batch: ALL shfls -> ALL loads -> ALL fmas.
__global__ __launch_bounds__(256) void agg_kernel(
    const unsigned char* __restrict__ egoq, const int* __restrict__ row_start,
    const unsigned* __restrict__ cv, unsigned* __restrict__ sideb) {
  int wid = threadIdx.x >> 6, lane = threadIdx.x & 63;
  int row = blockIdx.x * 4 + wid;
  if (row >= NN) return;
  int s = row_start[row], e = row_start[row + 1];
  int q = lane >> 4, ql = lane & 15;
  bool act = ql < 12;
  int ql8 = ql * 8;

  float a[4][8];
#pragma unroll
  for (int d = 0; d < 4; ++d)
#pragma unroll
    for (int j = 0; j < 8; ++j) a[d][j] = 0.f;

  for (int base = s; base < e; base += 64) {
    int idx = base + lane;
    unsigned pk = 0;
    if (idx < e) pk = cv[idx];
    int n = min(64, e - base);
    for (int i = 0; i < n; i += 16) {
      // phase 1: broadcast 4 packed entries to this quarter
      unsigned p[4];
#pragma unroll
      for (int d = 0; d < 4; ++d) p[d] = __shfl(pk, i + 4 * d + q, 64);
      // phase 2: issue all loads (16 gathers in flight per wave)
      uint2 u[4];
      float sc[4];
#pragma unroll
      for (int d = 0; d < 4; ++d) {
        const char* rowp = (const char*)egoq + ((size_t)(p[d] & 0xFFFFu) << 7);
        if (act) {
          u[d] = *(const uint2*)(rowp + ql8);
          sc[d] = *(const float*)(rowp + DD);
        } else {
          u[d] = make_uint2(0u, 0u);
          sc[d] = 0.f;
        }
      }
      // phase 3: fma everything
#pragma unroll
      for (int d = 0; d < 4; ++d) {
        float vs = bfhi(p[d]) * sc[d];
        a[d][0] += vs * sb(u[d].x, 0);
        a[d][1] += vs * sb(u[d].x, 1);
        a[d][2] += vs * sb(u[d].x, 2);
        a[d][3] += vs * sb(u[d].x, 3);
        a[d][4] += vs * sb(u[d].y, 0);
        a[d][5] += vs * sb(u[d].y, 1);
        a[d][6] += vs * sb(u[d].y, 2);
        a[d][7] += vs * sb(u[d].y, 3);
      }
    }
  }

  float r[8];
#pragma unroll
  for (int j = 0; j < 8; ++j) {
    r[j] = (a[0][j] + a[1][j]) + (a[2][j] + a[3][j]);
    r[j] += __shfl_xor(r[j], 16, 64);
    r[j] += __shfl_xor(r[j], 32, 64);
  }
  if (q == 0 && act) {
    uint4 o;
    o.x = (unsigned)f2bf(r[0]) | ((unsigned)f2bf(r[1]) << 16);
    o.y = (unsigned)f2bf(r[2]) | ((unsigned)f2bf(r[3]) << 16);
    o.z = (unsigned)f2bf(r[4]) | ((unsigned)f2bf(r[5]) << 16);
    o.w = (unsigned)f2bf(r[6]) | ((unsigned)f2bf(r[7]) << 16);
    *(uint4*)(sideb + (size_t)row * 48 + ql * 4) = o;
  }
}

// ========== fuse4: bf16 MFMA, staged from egoq(int8)+sideb(bf16) ==========
__global__ __launch_bounds__(256) void fuse4_kernel(
    const unsigned char* __restrict__ egoq, const unsigned* __restrict__ sideb,
    const unsigned short* __restrict__ Wb1, const unsigned short* __restrict__ Wb2,
    const float* __restrict__ b1, const float* __restrict__ b2,
    float* __restrict__ out)
{
  __shared__ unsigned short xs[FN * XST];
  __shared__ unsigned short ys[FN * XST];
  int tid = threadIdx.x;
  int nbase = blockIdx.x * FN;

  // stage x=e+s, y=e*s as bf16; FN*24 dword units, 6 iters/thread
  for (int i = tid; i < FN * 24; i += 256) {
    int r = i / 24, u = i - r * 24;
    float e0 = 0.f, e1 = 0.f, e2 = 0.f, e3 = 0.f;
    float s0 = 0.f, s1 = 0.f, s2 = 0.f, s3 = 0.f;
    if (nbase + r < NN) {
      const char* rowp = (const char*)egoq + ((size_t)(nbase + r) << 7);
      float sc = *(const float*)(rowp + DD);
      unsigned uq = *(const unsigned*)(rowp + u * 4);
      e0 = sc * sb(uq, 0);
      e1 = sc * sb(uq, 1);
      e2 = sc * sb(uq, 2);
      e3 = sc * sb(uq, 3);
      uint2 sv = *(const uint2*)(sideb + (size_t)(nbase + r) * 48 + u * 2);
      s0 = bflo(sv.x); s1 = bfhi(sv.x);
      s2 = bflo(sv.y); s3 = bfhi(sv.y);
    }
    unsigned xlo = (unsigned)f2bf(e0 + s0) | ((unsigned)f2bf(e1 + s1) << 16);
    unsigned xhi = (unsigned)f2bf(e2 + s2) | ((unsigned)f2bf(e3 + s3) << 16);
    unsigned ylo = (unsigned)f2bf(e0 * s0) | ((unsigned)f2bf(e1 * s1) << 16);
    unsigned yhi = (unsigned)f2bf(e2 * s2) | ((unsigned)f2bf(e3 * s3) << 16);
    *(uint2*)(xs + r * XST + u * 4) = make_uint2(xlo, xhi);
    *(uint2*)(ys + r * XST + u * 4) = make_uint2(ylo, yhi);
  }
  __syncthreads();

  int w = tid >> 6, l = tid & 63;
  int lrow = l & 15, lk = l >> 4;

  f32x4 acc1[6], acc2[6];
#pragma unroll
  for (int t = 0; t < 6; ++t) {
    acc1[t] = (f32x4){0.f, 0.f, 0.f, 0.f};
    acc2[t] = (f32x4){0.f, 0.f, 0.f, 0.f};
  }

  const unsigned short* xrow = xs + (w * 16 + lrow) * XST + lk * 8;
  const unsigned short* yrow = ys + (w * 16 + lrow) * XST + lk * 8;

#pragma unroll
  for (int kk = 0; kk < 3; ++kk) {
    short8v ax = *(const short8v*)(xrow + kk * 32);
    short8v ay = *(const short8v*)(yrow + kk * 32);
    int kb = kk * 32 + lk * 8;
#pragma unroll
    for (int t = 0; t < 6; ++t) {
      int j = t * 16 + lrow;
      short8v bw1 = *(const short8v*)(Wb1 + j * DD + kb);
      short8v bw2 = *(const short8v*)(Wb2 + j * DD + kb);
      acc1[t] = __builtin_amdgcn_mfma_f32_16x16x32_bf16(ax, bw1, acc1[t], 0, 0, 0);
      acc2[t] = __builtin_amdgcn_mfma_f32_16x16x32_bf16(ay, bw2, acc2[t], 0, 0, 0);
    }
  }

  int node0 = nbase + w * 16 + lk * 4;
#pragma unroll
  for (int t = 0; t < 6; ++t) {
    int j = t * 16 + lrow;
    float bb1 = b1[j], bb2 = b2[j];
#pragma unroll
    for (int i = 0; i < 4; ++i) {
      int node = node0 + i;
      if (node < NN)
        out[(size_t)node * DD + j] = lrelu(acc1[t][i] + bb1) + lrelu(acc2[t][i] + bb2);
    }
  }
}

// ================= launch =================
extern "C" void kernel_launch(void* const* d_in, const int* in_sizes, int n_in,
                              void* d_out, int out_size, void* d_ws, size_t ws_size,
                              hipStream_t stream) {
  const float* ego   = (const float*)d_in[0];
  const float* avals = (const float*)d_in[1];
  const float* W1    = (const float*)d_in[2];
  const float* b1    = (const float*)d_in[3];
  const float* W2    = (const float*)d_in[4];
  const float* b2    = (const float*)d_in[5];
  const int* arows   = (const int*)d_in[6];
  const int* acols   = (const int*)d_in[7];
  float* out = (float*)d_out;

  size_t off = 0;
  auto bump = [&](size_t bytes) {
    size_t o = off;
    off += (bytes + 1023) & ~(size_t)1023;
    return o;
  };
  char* ws = (char*)d_ws;
  size_t o_rs    = bump((size_t)(NN + 1) * 4);
  size_t o_cv    = bump((size_t)NE * 4);
  size_t o_wb1   = bump((size_t)DD * DD * 2);
  size_t o_wb2   = bump((size_t)DD * DD * 2);
  size_t o_egoq  = bump((size_t)NN * QROW);       // 6.4 MB int8 rows w/ scale
  size_t o_bptr  = bump((size_t)(NBK + 1) * 4);   // bptr[NBK] + ovcur
  size_t o_ovbuf = bump((size_t)OVCAP * 8);
  size_t o_sideb = bump((size_t)NN * DD * 2);     // 9.6 MB; buckets alias here
  size_t need = off;
  static_assert((size_t)NBK * BCAP * 8 <= (size_t)NN * DD * 2, "buckets fit in sideb");

  if (ws_size >= need) {
    int*  rs    = (int*)(ws + o_rs);
    unsigned* cv = (unsigned*)(ws + o_cv);
    unsigned short* Wb1  = (unsigned short*)(ws + o_wb1);
    unsigned short* Wb2  = (unsigned short*)(ws + o_wb2);
    unsigned char* egoq  = (unsigned char*)(ws + o_egoq);
    int*  bptr  = (int*)(ws + o_bptr);
    int*  ovcur = bptr + NBK;
    int2* ovbuf = (int2*)(ws + o_ovbuf);
    unsigned* sideb = (unsigned*)(ws + o_sideb);
    int2* buckets = (int2*)(ws + o_sideb);

    hipMemsetAsync(bptr, 0, (size_t)(NBK + 1) * 4, stream);
    build_kernel<<<NBA + NB_W + NB_Q, 256, 0, stream>>>(
        arows, acols, avals, bptr, ovcur, ovbuf, buckets,
        W1, W2, Wb1, Wb2, ego, egoq);
    binB_kernel<<<NBK, 256, 0, stream>>>(buckets, bptr, ovcur, ovbuf, cv, rs);
    agg_kernel<<<(NN + 3) / 4, 256, 0, stream>>>(egoq, rs, cv, sideb);
    fuse4_kernel<<<(NN + FN - 1) / FN, 256, 0, stream>>>(
        egoq, sideb, Wb1, Wb2, b1, b2, out);
  } else {
    size_t side_bytes = (size_t)NN * DD * sizeof(float);
    float* side = (ws_size >= side_bytes) ? (float*)d_ws : out;
    hipMemsetAsync(side, 0, side_bytes, stream);
    long long nthreads = (long long)NE * 32;
    int blocks = (int)((nthreads + 255) / 256);
    scatter_kernel<<<blocks, 256, 0, stream>>>(ego, avals, arows, acols, side);
    fuse_fb_kernel<<<1024, 192, 0, stream>>>(ego, side, W1, b1, W2, b2, out);
  }
}